// Round 6
// baseline (846.696 us; speedup 1.0000x reference)
//
#include <hip/hip_runtime.h>
#include <hip/hip_bf16.h>

#define NIN  512
#define NHID 256
#define NOUT 64
#define HOPS 10
#define NB   64          // bucket slots (49 used: row >> 11, N=100000)

typedef __attribute__((ext_vector_type(8))) short bf16x8;
typedef __attribute__((ext_vector_type(4))) float f32x4;

__device__ __forceinline__ unsigned short f2bf(float f) {
    unsigned u = __float_as_uint(f);
    u += 0x7FFFu + ((u >> 16) & 1u);            // RNE
    return (unsigned short)(u >> 16);
}
__device__ __forceinline__ unsigned pk2(float a, float b) {
    return (unsigned)f2bf(a) | ((unsigned)f2bf(b) << 16);
}
__device__ __forceinline__ float bflo(unsigned g) { return __uint_as_float(g << 16); }
__device__ __forceinline__ float bfhi(unsigned g) { return __uint_as_float(g & 0xFFFF0000u); }

// ---------------------------------------------------------------------------
// Pre-permute W1, W2 into MFMA A-fragment order (bf16).  (verified R4)
// ---------------------------------------------------------------------------
__global__ void k_preconv(const float* __restrict__ W1, const float* __restrict__ W2,
                          unsigned short* __restrict__ W1f, unsigned short* __restrict__ W2f)
{
    const int i = blockIdx.x * 256 + threadIdx.x;
    if (i < NHID * NIN) {
        const int j = i & 7, l = (i >> 3) & 63, fi = i >> 9;
        const int ks = fi >> 4, w = (fi >> 2) & 3, nf = fi & 3;
        const int col = w * 64 + nf * 16 + (l & 15);
        const int k   = ks * 32 + ((l >> 4) << 3) + j;
        W1f[i] = f2bf(W1[col * NIN + k]);
    }
    if (i < NOUT * NHID) {
        const int j = i & 7, l = (i >> 3) & 63, fi = i >> 9;
        const int ks = fi >> 2, nf = fi & 3;
        const int col = nf * 16 + (l & 15);
        const int k   = ks * 32 + ((j >> 2) << 4) + ((l >> 4) << 2) + (j & 3);
        W2f[i] = f2bf(W2[col * NHID + k]);
    }
}

// ---------------------------------------------------------------------------
// Fused MFMA MLP (operand-swapped, verified R4/R5). Outputs bf16-packed h0
// and sig0. 3 blocks/CU (LDS 3x50.7KB fits 160KB; VGPR 68 << 170).
// ---------------------------------------------------------------------------
__global__ __launch_bounds__(256, 3) void mlp_kernel(
    const float* __restrict__ x, const unsigned short* __restrict__ W1f,
    const float* __restrict__ b1, const unsigned short* __restrict__ W2f,
    const float* __restrict__ b2, const float* __restrict__ s,
    unsigned* __restrict__ hpack, float* __restrict__ sigbuf, int n)
{
    __shared__ __align__(16) char smem[50432];
    short* B2L  = (short*)smem;
    short* BX   = (short*)(smem + 32768);
    float* H0L  = (float*)(smem + 32768);
    float* SIGL = (float*)(smem + 50176);

    const int t  = threadIdx.x;
    const int w  = t >> 6, lz = t & 63;
    const int row0 = blockIdx.x * 64;

    const int srow = t >> 2;
    int xrow = row0 + srow; if (xrow >= n) xrow = n - 1;
    const float4* xp = (const float4*)(x + (size_t)xrow * NIN);
    const int q4a = t & 3, q4b = (t & 3) + 4;

    f32x4 acc[4][4];
    #pragma unroll
    for (int a = 0; a < 4; ++a)
        #pragma unroll
        for (int b = 0; b < 4; ++b) acc[a][b] = (f32x4)(0.f);

    auto xwrite = [&](int b, float4 va, float4 vb) {
        unsigned long long pa = (unsigned long long)pk2(va.x, va.y)
                              | ((unsigned long long)pk2(va.z, va.w) << 32);
        unsigned long long pb = (unsigned long long)pk2(vb.x, vb.y)
                              | ((unsigned long long)pk2(vb.z, vb.w) << 32);
        *(unsigned long long*)&BX[(((((b << 2) + (srow >> 4)) << 6)
            + ((srow & 15) | ((q4a >> 1) << 4))) << 3) + ((q4a & 1) << 2)] = pa;
        *(unsigned long long*)&BX[(((((b << 2) + (srow >> 4)) << 6)
            + ((srow & 15) | ((q4b >> 1) << 4))) << 3) + ((q4b & 1) << 2)] = pb;
    };
    auto compute = [&](int b, int kt) {
        bf16x8 xf[4], wf[4];
        #pragma unroll
        for (int nfn = 0; nfn < 4; ++nfn)
            xf[nfn] = *(const bf16x8*)&BX[((((b << 2) + nfn) << 6) + lz) << 3];
        const unsigned short* wp = W1f + ((size_t)kt << 13) + (w << 11) + (lz << 3);
        #pragma unroll
        for (int hf = 0; hf < 4; ++hf)
            wf[hf] = *(const bf16x8*)(wp + (hf << 9));
        #pragma unroll
        for (int nfn = 0; nfn < 4; ++nfn)
            #pragma unroll
            for (int hf = 0; hf < 4; ++hf)
                acc[nfn][hf] = __builtin_amdgcn_mfma_f32_16x16x32_bf16(
                    wf[hf], xf[nfn], acc[nfn][hf], 0, 0, 0);
    };

    {
        float4 xa = xp[q4a], xb = xp[q4b];
        xwrite(0, xa, xb);
    }
    __syncthreads();

    #pragma unroll 1
    for (int kt = 0; kt < 16; ++kt) {
        const int b = kt & 1;
        float4 nxa, nxb;
        if (kt < 15) {
            nxa = xp[((kt + 1) << 3) + q4a];
            nxb = xp[((kt + 1) << 3) + q4b];
        }
        compute(b, kt);
        if (kt < 15) xwrite(b ^ 1, nxa, nxb);
        __syncthreads();
    }

    // ---- bias + relu + in-register repack -> B2L (h1^T B-fragments) -----
    {
        float4 b1q[4];
        #pragma unroll
        for (int hf = 0; hf < 4; ++hf)
            b1q[hf] = *(const float4*)(b1 + (w << 6) + (hf << 4) + ((lz >> 4) << 2));
        #pragma unroll
        for (int nfn = 0; nfn < 4; ++nfn) {
            #pragma unroll
            for (int cl = 0; cl < 2; ++cl) {
                f32x4 a0 = acc[nfn][2 * cl], a1 = acc[nfn][2 * cl + 1];
                float4 c0 = b1q[2 * cl], c1 = b1q[2 * cl + 1];
                uint4 pv;
                pv.x = pk2(fmaxf(a0.x + c0.x, 0.f), fmaxf(a0.y + c0.y, 0.f));
                pv.y = pk2(fmaxf(a0.z + c0.z, 0.f), fmaxf(a0.w + c0.w, 0.f));
                pv.z = pk2(fmaxf(a1.x + c1.x, 0.f), fmaxf(a1.y + c1.y, 0.f));
                pv.w = pk2(fmaxf(a1.z + c1.z, 0.f), fmaxf(a1.w + c1.w, 0.f));
                *(uint4*)&B2L[((((nfn << 3) + (w << 1) + cl) << 6) + lz) << 3] = pv;
            }
        }
    }
    __syncthreads();

    // ---- GEMM2: h0^T = W2 @ h1^T ----------------------------------------
    f32x4 acc2[4];
    #pragma unroll
    for (int nf2 = 0; nf2 < 4; ++nf2) acc2[nf2] = (f32x4)(0.f);

    #pragma unroll
    for (int c = 0; c < 8; ++c) {
        bf16x8 hfrag = *(const bf16x8*)&B2L[((((w << 3) + c) << 6) + lz) << 3];
        #pragma unroll
        for (int nf2 = 0; nf2 < 4; ++nf2) {
            bf16x8 wfrag = *(const bf16x8*)(W2f + (((c << 2) + nf2) << 9) + (lz << 3));
            acc2[nf2] = __builtin_amdgcn_mfma_f32_16x16x32_bf16(
                wfrag, hfrag, acc2[nf2], 0, 0, 0);
        }
    }

    // ---- epilogue: bias, attention dot, sigmoid, LDS reshape, stores -----
    {
        float dot = 0.f;
        #pragma unroll
        for (int nf2 = 0; nf2 < 4; ++nf2) {
            float4 bq = *(const float4*)(b2 + (nf2 << 4) + ((lz >> 4) << 2));
            float4 qv = *(const float4*)(s  + (nf2 << 4) + ((lz >> 4) << 2));
            acc2[nf2].x += bq.x; acc2[nf2].y += bq.y;
            acc2[nf2].z += bq.z; acc2[nf2].w += bq.w;
            dot += acc2[nf2].x * qv.x + acc2[nf2].y * qv.y
                 + acc2[nf2].z * qv.z + acc2[nf2].w * qv.w;
        }
        dot += __shfl_xor(dot, 16);
        dot += __shfl_xor(dot, 32);
        const float sig = 1.f / (1.f + expf(-dot));
        if (lz < 16) SIGL[(w << 4) + lz] = sig;
        const int mloc = (w << 4) + (lz & 15);
        #pragma unroll
        for (int nf2 = 0; nf2 < 4; ++nf2) {
            float4 hv; hv.x = acc2[nf2].x; hv.y = acc2[nf2].y;
            hv.z = acc2[nf2].z; hv.w = acc2[nf2].w;
            *(float4*)&H0L[mloc * 68 + (nf2 << 4) + ((lz >> 4) << 2)] = hv;
        }
    }
    __syncthreads();

    {
        const int m = t >> 2, q = t & 3;
        const int g = row0 + m;
        if (g < n) {
            unsigned* hp = hpack + (size_t)g * 32 + (q << 3);
            #pragma unroll
            for (int i = 0; i < 16; i += 4) {
                float4 hv = *(const float4*)&H0L[m * 68 + (q << 4) + i];
                uint2 pv;
                pv.x = pk2(hv.x, hv.y);
                pv.y = pk2(hv.z, hv.w);
                *(uint2*)(hp + (i >> 1)) = pv;
            }
        }
        if (t < 64 && row0 + t < n) sigbuf[row0 + t] = SIGL[t];
    }
}

// ---------------------------------------------------------------------------
// CSR build, two-stage bucketed:
//   k_count_hist: degree count + bucket histogram (bucket = row >> 11)
//   k_scan1/2/3:  hierarchical exclusive scan of degrees (+ bucket scan in 2)
//   k_bappend:    bin edges into append-ordered 16B records per bucket
//   k_scatter2:   within-bucket scatter to CSR slots (L2-confined windows)
// ---------------------------------------------------------------------------
__global__ void k_count_hist(const int* __restrict__ erow, int* __restrict__ deg,
                             int* __restrict__ bcnt, int e) {
    __shared__ int lh[NB];
    const int t = threadIdx.x;
    if (t < NB) lh[t] = 0;
    __syncthreads();
    const int i = blockIdx.x * 256 + t;
    if (i < e) {
        const int r = erow[i];
        atomicAdd(&deg[r], 1);
        atomicAdd(&lh[r >> 11], 1);
    }
    __syncthreads();
    if (t < NB && lh[t]) atomicAdd(&bcnt[t], lh[t]);
}

__global__ void k_scan1(const int* __restrict__ deg, int* __restrict__ rp,
                        int* __restrict__ bsum, int nv) {
    __shared__ int sm[256];
    const int i = blockIdx.x * 256 + threadIdx.x;
    const int v = (i < nv) ? deg[i] : 0;
    sm[threadIdx.x] = v;
    __syncthreads();
    for (int off = 1; off < 256; off <<= 1) {
        int tv = (threadIdx.x >= off) ? sm[threadIdx.x - off] : 0;
        __syncthreads();
        sm[threadIdx.x] += tv;
        __syncthreads();
    }
    if (i < nv) rp[i] = sm[threadIdx.x] - v;
    if (threadIdx.x == 255) bsum[blockIdx.x] = sm[255];
}

__global__ void k_scan2(int* __restrict__ bsum, int nb,
                        const int* __restrict__ bcnt, int* __restrict__ bcur) {
    __shared__ int sm[512];
    const int tid = threadIdx.x;
    const int v = (tid < nb) ? bsum[tid] : 0;
    sm[tid] = v;
    __syncthreads();
    for (int off = 1; off < 512; off <<= 1) {
        int tv = (tid >= off) ? sm[tid - off] : 0;
        __syncthreads();
        sm[tid] += tv;
        __syncthreads();
    }
    if (tid < nb) bsum[tid] = sm[tid] - v;
    // bucket exclusive scan (wave 0, 64 lanes)
    if (tid < NB) {
        int bv = bcnt[tid];
        int x = bv;
        #pragma unroll
        for (int off = 1; off < 64; off <<= 1) {
            int y = __shfl_up(x, off);
            if (tid >= off) x += y;
        }
        bcur[tid] = x - bv;
    }
}

__global__ void k_scan3(int* __restrict__ rp, int* __restrict__ cur,
                        const int* __restrict__ bsum, int nv, int e) {
    const int i = blockIdx.x * 256 + threadIdx.x;
    if (i < nv) {
        const int vv = rp[i] + bsum[blockIdx.x];
        rp[i]  = vv;
        cur[i] = vv;
    }
    if (i == 0) rp[nv] = e;
}

__global__ void k_bappend(const int* __restrict__ erow, const int* __restrict__ ecol,
                          const float* __restrict__ ev, int* __restrict__ bcur,
                          uint4* __restrict__ brec, int e) {
    __shared__ int lh[NB];      // block bucket counts
    __shared__ int lbase[NB];   // block's global base per bucket
    __shared__ int lrank[NB];   // running rank
    const int t = threadIdx.x;
    if (t < NB) lh[t] = 0;
    __syncthreads();
    const int i = blockIdx.x * 256 + t;
    const bool valid = i < e;
    int r = 0, b = 0;
    if (valid) { r = erow[i]; b = r >> 11; atomicAdd(&lh[b], 1); }
    __syncthreads();
    if (t < NB) {
        const int c = lh[t];
        lbase[t] = c ? atomicAdd(&bcur[t], c) : 0;
        lrank[t] = 0;
    }
    __syncthreads();
    if (valid) {
        const int rk = atomicAdd(&lrank[b], 1);
        uint4 rec;
        rec.x = (unsigned)r;
        rec.y = (unsigned)ecol[i];
        rec.z = __float_as_uint(ev[i]);
        rec.w = 0;
        brec[lbase[b] + rk] = rec;
    }
}

__global__ void k_scatter2(const uint4* __restrict__ brec, int* __restrict__ cur,
                           unsigned long long* __restrict__ cpack, int e) {
    const int i = blockIdx.x * 256 + threadIdx.x;
    if (i < e) {
        const uint4 rec = brec[i];
        const int p = atomicAdd(&cur[rec.x], 1);
        cpack[p] = ((unsigned long long)rec.z << 32) | rec.y;
    }
}

// ---------------------------------------------------------------------------
// One propagation hop (pull, CSR, bf16-packed h). 32 lanes = 1 node.
// ---------------------------------------------------------------------------
__global__ __launch_bounds__(256) void hop_kernel(
    const unsigned* __restrict__ h_in, unsigned* __restrict__ h_out,
    const int* __restrict__ row_ptr, const unsigned long long* __restrict__ cpack,
    const float* __restrict__ s, float* __restrict__ sig_out, int n)
{
    const int t  = threadIdx.x;
    const int sl = t & 31;
    const int node = (blockIdx.x * 256 + t) >> 5;
    if (node >= n) return;
    const int start = row_ptr[node];
    const int end   = row_ptr[node + 1];
    float a0 = 0.f, a1 = 0.f;
    for (int base = start; base < end; base += 32) {
        const int idx = base + sl;
        unsigned long long pc = (idx < end) ? cpack[idx] : 0ULL;
        int   c = (int)(unsigned)pc;
        float v = __uint_as_float((unsigned)(pc >> 32));
        const int cnt = min(32, end - base);
        int e = 0;
        for (; e + 4 <= cnt; e += 4) {
            int   c0 = __shfl(c, e, 32),     c1 = __shfl(c, e + 1, 32);
            int   c2 = __shfl(c, e + 2, 32), c3 = __shfl(c, e + 3, 32);
            float v0 = __shfl(v, e, 32),     v1 = __shfl(v, e + 1, 32);
            float v2 = __shfl(v, e + 2, 32), v3 = __shfl(v, e + 3, 32);
            unsigned g0 = h_in[(size_t)c0 * 32 + sl];
            unsigned g1 = h_in[(size_t)c1 * 32 + sl];
            unsigned g2 = h_in[(size_t)c2 * 32 + sl];
            unsigned g3 = h_in[(size_t)c3 * 32 + sl];
            a0 = fmaf(v0, bflo(g0), a0); a1 = fmaf(v0, bfhi(g0), a1);
            a0 = fmaf(v1, bflo(g1), a0); a1 = fmaf(v1, bfhi(g1), a1);
            a0 = fmaf(v2, bflo(g2), a0); a1 = fmaf(v2, bfhi(g2), a1);
            a0 = fmaf(v3, bflo(g3), a0); a1 = fmaf(v3, bfhi(g3), a1);
        }
        for (; e < cnt; ++e) {
            int   cc = __shfl(c, e, 32);
            float vv = __shfl(v, e, 32);
            unsigned g = h_in[(size_t)cc * 32 + sl];
            a0 = fmaf(vv, bflo(g), a0); a1 = fmaf(vv, bfhi(g), a1);
        }
    }
    const float2 sv = ((const float2*)s)[sl];
    float tv = a0 * sv.x + a1 * sv.y;
    #pragma unroll
    for (int off = 16; off > 0; off >>= 1) tv += __shfl_xor(tv, off, 32);
    h_out[(size_t)node * 32 + sl] = pk2(a0, a1);
    if (sl == 0) sig_out[node] = 1.f / (1.f + expf(-tv));
}

// ---------------------------------------------------------------------------
// Final combine: out[n][64] = sum_k sig_k(n) * h_k(n)   (fp32 output)
// ---------------------------------------------------------------------------
__global__ __launch_bounds__(256) void k_combine(
    const unsigned* __restrict__ hbuf, const float* __restrict__ sigbuf,
    float* __restrict__ out, int n)
{
    const int gid  = blockIdx.x * 256 + threadIdx.x;
    const int node = gid >> 5, sl = gid & 31;
    if (node >= n) return;
    float o0 = 0.f, o1 = 0.f;
    #pragma unroll
    for (int k = 0; k <= HOPS; ++k) {
        const unsigned g = hbuf[(size_t)k * n * 32 + (size_t)node * 32 + sl];
        const float sg = sigbuf[(size_t)k * n + node];
        o0 = fmaf(sg, bflo(g), o0);
        o1 = fmaf(sg, bfhi(g), o1);
    }
    float2 ov; ov.x = o0; ov.y = o1;
    ((float2*)out)[(size_t)node * 32 + sl] = ov;
}

// ---------------------------------------------------------------------------
extern "C" void kernel_launch(void* const* d_in, const int* in_sizes, int n_in,
                              void* d_out, int out_size, void* d_ws, size_t ws_size,
                              hipStream_t stream)
{
    const float* x  = (const float*)d_in[0];
    const int*   er = (const int*)  d_in[1];
    const int*   ec = (const int*)  d_in[2];
    const float* ev = (const float*)d_in[3];
    const float* W1 = (const float*)d_in[4];
    const float* b1 = (const float*)d_in[5];
    const float* W2 = (const float*)d_in[6];
    const float* b2 = (const float*)d_in[7];
    const float* s  = (const float*)d_in[8];
    float* out = (float*)d_out;

    const int n = in_sizes[0] / NIN;   // 100000
    const int e = in_sizes[1];         // 1600000

    // workspace carve (256B aligned): ~190 MB of ~800 MB ws
    char* w = (char*)d_ws;
    auto carve = [&](size_t bytes) { char* p = w; w += (bytes + 255) & ~(size_t)255; return p; };
    unsigned* hbuf   = (unsigned*)carve((size_t)(HOPS + 1) * n * 32 * 4);  // 140.8 MB
    float*    sigbuf = (float*)   carve((size_t)(HOPS + 1) * n * 4);       // 4.4 MB
    int*      deg    = (int*)     carve((size_t)n * 4);
    int*      rp     = (int*)     carve(((size_t)n + 1) * 4);
    int*      cur    = (int*)     carve((size_t)n * 4);
    unsigned long long* cpack = (unsigned long long*)carve((size_t)e * 8); // 12.8 MB
    uint4*    brec   = (uint4*)   carve((size_t)e * 16);                   // 25.6 MB
    int*      bsum   = (int*)     carve(1024 * 4);
    int*      bcnt   = (int*)     carve(NB * 4);
    int*      bcur   = (int*)     carve(NB * 4);
    unsigned short* W1f = (unsigned short*)carve((size_t)NHID * NIN * 2);
    unsigned short* W2f = (unsigned short*)carve((size_t)NOUT * NHID * 2);

    hipMemsetAsync(deg, 0, (size_t)n * 4, stream);
    hipMemsetAsync(bcnt, 0, NB * 4, stream);

    k_preconv<<<(NHID * NIN + 255) / 256, 256, 0, stream>>>(W1, W2, W1f, W2f);

    const int mgrid = (n + 63) / 64;
    mlp_kernel<<<mgrid, 256, 0, stream>>>(x, W1f, b1, W2f, b2, s,
                                          hbuf, sigbuf, n);

    const int eg = (e + 255) / 256;
    const int nb = (n + 255) / 256;
    k_count_hist<<<eg, 256, 0, stream>>>(er, deg, bcnt, e);
    k_scan1     <<<nb, 256, 0, stream>>>(deg, rp, bsum, n);
    k_scan2     <<<1, 512, 0, stream>>>(bsum, nb, bcnt, bcur);
    k_scan3     <<<nb, 256, 0, stream>>>(rp, cur, bsum, n, e);
    k_bappend   <<<eg, 256, 0, stream>>>(er, ec, ev, bcur, brec, e);
    k_scatter2  <<<eg, 256, 0, stream>>>(brec, cur, cpack, e);

    const int hgrid = ((size_t)n * 32 + 255) / 256;
    for (int hop = 0; hop < HOPS; ++hop) {
        hop_kernel<<<hgrid, 256, 0, stream>>>(
            hbuf + (size_t)hop * n * 32, hbuf + (size_t)(hop + 1) * n * 32,
            rp, cpack, s, sigbuf + (size_t)(hop + 1) * n, n);
    }

    k_combine<<<hgrid, 256, 0, stream>>>(hbuf, sigbuf, out, n);
}

// Round 7
// 630.966 us; speedup vs baseline: 1.3419x; 1.3419x over previous
//
#include <hip/hip_runtime.h>
#include <hip/hip_bf16.h>

#define NIN  512
#define NHID 256
#define NOUT 64
#define HOPS 10

typedef __attribute__((ext_vector_type(8))) short bf16x8;
typedef __attribute__((ext_vector_type(4))) float f32x4;

__device__ __forceinline__ unsigned short f2bf(float f) {
    unsigned u = __float_as_uint(f);
    u += 0x7FFFu + ((u >> 16) & 1u);            // RNE
    return (unsigned short)(u >> 16);
}
__device__ __forceinline__ unsigned pk2(float a, float b) {
    return (unsigned)f2bf(a) | ((unsigned)f2bf(b) << 16);
}
__device__ __forceinline__ float bflo(unsigned g) { return __uint_as_float(g << 16); }
__device__ __forceinline__ float bfhi(unsigned g) { return __uint_as_float(g & 0xFFFF0000u); }

// ---------------------------------------------------------------------------
// Pre-permute W1, W2 into MFMA A-fragment order (bf16).  (verified R4/R5)
// ---------------------------------------------------------------------------
__global__ void k_preconv(const float* __restrict__ W1, const float* __restrict__ W2,
                          unsigned short* __restrict__ W1f, unsigned short* __restrict__ W2f)
{
    const int i = blockIdx.x * 256 + threadIdx.x;
    if (i < NHID * NIN) {
        const int j = i & 7, l = (i >> 3) & 63, fi = i >> 9;
        const int ks = fi >> 4, w = (fi >> 2) & 3, nf = fi & 3;
        const int col = w * 64 + nf * 16 + (l & 15);
        const int k   = ks * 32 + ((l >> 4) << 3) + j;
        W1f[i] = f2bf(W1[col * NIN + k]);
    }
    if (i < NOUT * NHID) {
        const int j = i & 7, l = (i >> 3) & 63, fi = i >> 9;
        const int ks = fi >> 2, nf = fi & 3;
        const int col = nf * 16 + (l & 15);
        const int k   = ks * 32 + ((j >> 2) << 4) + ((l >> 4) << 2) + (j & 3);
        W2f[i] = f2bf(W2[col * NHID + k]);
    }
}

// ---------------------------------------------------------------------------
// Fused MFMA MLP (operand-swapped, verified R4/R5). Outputs bf16-packed h0.
// 3 blocks/CU; W1f fragments register-prefetched across the kt loop.
// Attention sig deferred to k_combine.
// ---------------------------------------------------------------------------
__global__ __launch_bounds__(256, 3) void mlp_kernel(
    const float* __restrict__ x, const unsigned short* __restrict__ W1f,
    const float* __restrict__ b1, const unsigned short* __restrict__ W2f,
    const float* __restrict__ b2,
    unsigned* __restrict__ hpack, int n)
{
    // LDS overlay: [0,32768)        B2L [4][8][64][8] h1^T frags (GEMM2 phase)
    //              [32768, +8192)   BX  [2][4][64][8] x frags (GEMM1 dbuf)
    //              [32768, +17408)  H0L [64][68] f32 (epilogue, after BX dead)
    __shared__ __align__(16) char smem[50176];
    short* B2L  = (short*)smem;
    short* BX   = (short*)(smem + 32768);
    float* H0L  = (float*)(smem + 32768);

    const int t  = threadIdx.x;
    const int w  = t >> 6, lz = t & 63;
    const int row0 = blockIdx.x * 64;

    const int srow = t >> 2;
    int xrow = row0 + srow; if (xrow >= n) xrow = n - 1;
    const float4* xp = (const float4*)(x + (size_t)xrow * NIN);
    const int q4a = t & 3, q4b = (t & 3) + 4;

    f32x4 acc[4][4];
    #pragma unroll
    for (int a = 0; a < 4; ++a)
        #pragma unroll
        for (int b = 0; b < 4; ++b) acc[a][b] = (f32x4)(0.f);

    auto xwrite = [&](int b, float4 va, float4 vb) {
        unsigned long long pa = (unsigned long long)pk2(va.x, va.y)
                              | ((unsigned long long)pk2(va.z, va.w) << 32);
        unsigned long long pb = (unsigned long long)pk2(vb.x, vb.y)
                              | ((unsigned long long)pk2(vb.z, vb.w) << 32);
        *(unsigned long long*)&BX[(((((b << 2) + (srow >> 4)) << 6)
            + ((srow & 15) | ((q4a >> 1) << 4))) << 3) + ((q4a & 1) << 2)] = pa;
        *(unsigned long long*)&BX[(((((b << 2) + (srow >> 4)) << 6)
            + ((srow & 15) | ((q4b >> 1) << 4))) << 3) + ((q4b & 1) << 2)] = pb;
    };
    auto wload = [&](int kt, bf16x8* wf) {
        const unsigned short* wp = W1f + ((size_t)kt << 13) + (w << 11) + (lz << 3);
        #pragma unroll
        for (int hf = 0; hf < 4; ++hf)
            wf[hf] = *(const bf16x8*)(wp + (hf << 9));   // coalesced, L2-resident
    };
    auto compute = [&](int b, const bf16x8* wf) {
        bf16x8 xf[4];
        #pragma unroll
        for (int nfn = 0; nfn < 4; ++nfn)
            xf[nfn] = *(const bf16x8*)&BX[((((b << 2) + nfn) << 6) + lz) << 3];
        #pragma unroll
        for (int nfn = 0; nfn < 4; ++nfn)
            #pragma unroll
            for (int hf = 0; hf < 4; ++hf)
                acc[nfn][hf] = __builtin_amdgcn_mfma_f32_16x16x32_bf16(
                    wf[hf], xf[nfn], acc[nfn][hf], 0, 0, 0);   // A=W1, B=x^T
    };

    bf16x8 wfc[4], wfn[4];
    {
        float4 xa = xp[q4a], xb = xp[q4b];
        wload(0, wfc);
        xwrite(0, xa, xb);
    }
    __syncthreads();

    #pragma unroll 1
    for (int kt = 0; kt < 16; ++kt) {
        const int b = kt & 1;
        float4 nxa, nxb;
        if (kt < 15) {
            nxa = xp[((kt + 1) << 3) + q4a];
            nxb = xp[((kt + 1) << 3) + q4b];
            wload(kt + 1, wfn);
        }
        compute(b, wfc);
        if (kt < 15) {
            xwrite(b ^ 1, nxa, nxb);
            #pragma unroll
            for (int hf = 0; hf < 4; ++hf) wfc[hf] = wfn[hf];
        }
        __syncthreads();
    }

    // ---- bias + relu + in-register repack -> B2L (h1^T B-fragments) -----
    {
        float4 b1q[4];
        #pragma unroll
        for (int hf = 0; hf < 4; ++hf)
            b1q[hf] = *(const float4*)(b1 + (w << 6) + (hf << 4) + ((lz >> 4) << 2));
        #pragma unroll
        for (int nfn = 0; nfn < 4; ++nfn) {
            #pragma unroll
            for (int cl = 0; cl < 2; ++cl) {
                f32x4 a0 = acc[nfn][2 * cl], a1 = acc[nfn][2 * cl + 1];
                float4 c0 = b1q[2 * cl], c1 = b1q[2 * cl + 1];
                uint4 pv;
                pv.x = pk2(fmaxf(a0.x + c0.x, 0.f), fmaxf(a0.y + c0.y, 0.f));
                pv.y = pk2(fmaxf(a0.z + c0.z, 0.f), fmaxf(a0.w + c0.w, 0.f));
                pv.z = pk2(fmaxf(a1.x + c1.x, 0.f), fmaxf(a1.y + c1.y, 0.f));
                pv.w = pk2(fmaxf(a1.z + c1.z, 0.f), fmaxf(a1.w + c1.w, 0.f));
                *(uint4*)&B2L[((((nfn << 3) + (w << 1) + cl) << 6) + lz) << 3] = pv;
            }
        }
    }
    __syncthreads();

    // ---- GEMM2: h0^T = W2 @ h1^T ----------------------------------------
    f32x4 acc2[4];
    #pragma unroll
    for (int nf2 = 0; nf2 < 4; ++nf2) acc2[nf2] = (f32x4)(0.f);

    #pragma unroll
    for (int c = 0; c < 8; ++c) {
        bf16x8 hfrag = *(const bf16x8*)&B2L[((((w << 3) + c) << 6) + lz) << 3];
        #pragma unroll
        for (int nf2 = 0; nf2 < 4; ++nf2) {
            bf16x8 wfrag = *(const bf16x8*)(W2f + (((c << 2) + nf2) << 9) + (lz << 3));
            acc2[nf2] = __builtin_amdgcn_mfma_f32_16x16x32_bf16(
                wfrag, hfrag, acc2[nf2], 0, 0, 0);
        }
    }

    // ---- epilogue: bias, LDS reshape, packed stores ----------------------
    {
        const int mloc = (w << 4) + (lz & 15);
        #pragma unroll
        for (int nf2 = 0; nf2 < 4; ++nf2) {
            float4 bq = *(const float4*)(b2 + (nf2 << 4) + ((lz >> 4) << 2));
            float4 hv;
            hv.x = acc2[nf2].x + bq.x; hv.y = acc2[nf2].y + bq.y;
            hv.z = acc2[nf2].z + bq.z; hv.w = acc2[nf2].w + bq.w;
            *(float4*)&H0L[mloc * 68 + (nf2 << 4) + ((lz >> 4) << 2)] = hv;
        }
    }
    __syncthreads();

    {
        const int m = t >> 2, q = t & 3;
        const int g = row0 + m;
        if (g < n) {
            unsigned* hp = hpack + (size_t)g * 32 + (q << 3);
            #pragma unroll
            for (int i = 0; i < 16; i += 4) {
                float4 hv = *(const float4*)&H0L[m * 68 + (q << 4) + i];
                uint2 pv;
                pv.x = pk2(hv.x, hv.y);
                pv.y = pk2(hv.z, hv.w);
                *(uint2*)(hp + (i >> 1)) = pv;
            }
        }
    }
}

// ---------------------------------------------------------------------------
// CSR build: degree count -> hierarchical exclusive scan -> packed scatter
// (R5-verified versions)
// ---------------------------------------------------------------------------
__global__ void k_count(const int* __restrict__ erow, int* __restrict__ deg, int e) {
    int i = blockIdx.x * 256 + threadIdx.x;
    if (i < e) atomicAdd(&deg[erow[i]], 1);
}

__global__ void k_scan1(const int* __restrict__ deg, int* __restrict__ rp,
                        int* __restrict__ bsum, int nv) {
    __shared__ int sm[256];
    const int i = blockIdx.x * 256 + threadIdx.x;
    const int v = (i < nv) ? deg[i] : 0;
    sm[threadIdx.x] = v;
    __syncthreads();
    for (int off = 1; off < 256; off <<= 1) {
        int tv = (threadIdx.x >= off) ? sm[threadIdx.x - off] : 0;
        __syncthreads();
        sm[threadIdx.x] += tv;
        __syncthreads();
    }
    if (i < nv) rp[i] = sm[threadIdx.x] - v;
    if (threadIdx.x == 255) bsum[blockIdx.x] = sm[255];
}

__global__ void k_scan2(int* __restrict__ bsum, int nb) {
    __shared__ int sm[512];
    const int tid = threadIdx.x;
    const int v = (tid < nb) ? bsum[tid] : 0;
    sm[tid] = v;
    __syncthreads();
    for (int off = 1; off < 512; off <<= 1) {
        int tv = (tid >= off) ? sm[tid - off] : 0;
        __syncthreads();
        sm[tid] += tv;
        __syncthreads();
    }
    if (tid < nb) bsum[tid] = sm[tid] - v;
}

__global__ void k_scan3(int* __restrict__ rp, int* __restrict__ cur,
                        const int* __restrict__ bsum, int nv, int e) {
    const int i = blockIdx.x * 256 + threadIdx.x;
    if (i < nv) {
        const int vv = rp[i] + bsum[blockIdx.x];
        rp[i]  = vv;
        cur[i] = vv;
    }
    if (i == 0) rp[nv] = e;
}

__global__ void k_scatter(const int* __restrict__ erow, const int* __restrict__ ecol,
                          const float* __restrict__ ev, int* __restrict__ cur,
                          unsigned long long* __restrict__ cpack, int e) {
    const int i = blockIdx.x * 256 + threadIdx.x;
    if (i < e) {
        const int r = erow[i];
        const int p = atomicAdd(&cur[r], 1);
        cpack[p] = ((unsigned long long)__float_as_uint(ev[i]) << 32)
                 | (unsigned)ecol[i];
    }
}

// ---------------------------------------------------------------------------
// One propagation hop (pull, CSR, bf16-packed h). Pure SpMM; sig deferred.
// 32 lanes = 1 node (2 features/lane).
// ---------------------------------------------------------------------------
__global__ __launch_bounds__(256) void hop_kernel(
    const unsigned* __restrict__ h_in, unsigned* __restrict__ h_out,
    const int* __restrict__ row_ptr, const unsigned long long* __restrict__ cpack,
    int n)
{
    const int t  = threadIdx.x;
    const int sl = t & 31;
    const int node = (blockIdx.x * 256 + t) >> 5;
    if (node >= n) return;
    const int start = row_ptr[node];
    const int end   = row_ptr[node + 1];
    float a0 = 0.f, a1 = 0.f;
    for (int base = start; base < end; base += 32) {
        const int idx = base + sl;
        unsigned long long pc = (idx < end) ? cpack[idx] : 0ULL;
        int   c = (int)(unsigned)pc;
        float v = __uint_as_float((unsigned)(pc >> 32));
        const int cnt = min(32, end - base);
        int e = 0;
        for (; e + 4 <= cnt; e += 4) {           // 4 gathers in flight
            int   c0 = __shfl(c, e, 32),     c1 = __shfl(c, e + 1, 32);
            int   c2 = __shfl(c, e + 2, 32), c3 = __shfl(c, e + 3, 32);
            float v0 = __shfl(v, e, 32),     v1 = __shfl(v, e + 1, 32);
            float v2 = __shfl(v, e + 2, 32), v3 = __shfl(v, e + 3, 32);
            unsigned g0 = h_in[(size_t)c0 * 32 + sl];
            unsigned g1 = h_in[(size_t)c1 * 32 + sl];
            unsigned g2 = h_in[(size_t)c2 * 32 + sl];
            unsigned g3 = h_in[(size_t)c3 * 32 + sl];
            a0 = fmaf(v0, bflo(g0), a0); a1 = fmaf(v0, bfhi(g0), a1);
            a0 = fmaf(v1, bflo(g1), a0); a1 = fmaf(v1, bfhi(g1), a1);
            a0 = fmaf(v2, bflo(g2), a0); a1 = fmaf(v2, bfhi(g2), a1);
            a0 = fmaf(v3, bflo(g3), a0); a1 = fmaf(v3, bfhi(g3), a1);
        }
        for (; e < cnt; ++e) {
            int   cc = __shfl(c, e, 32);
            float vv = __shfl(v, e, 32);
            unsigned g = h_in[(size_t)cc * 32 + sl];
            a0 = fmaf(vv, bflo(g), a0); a1 = fmaf(vv, bfhi(g), a1);
        }
    }
    h_out[(size_t)node * 32 + sl] = pk2(a0, a1);
}

// ---------------------------------------------------------------------------
// Final combine: sig_k(n) = sigmoid(h_k(n).s); out = sum_k sig_k(n) h_k(n)
// ---------------------------------------------------------------------------
__global__ __launch_bounds__(256) void k_combine(
    const unsigned* __restrict__ hbuf, const float* __restrict__ s,
    float* __restrict__ out, int n)
{
    const int gid  = blockIdx.x * 256 + threadIdx.x;
    const int node = gid >> 5, sl = gid & 31;
    if (node >= n) return;
    const float2 sv = ((const float2*)s)[sl];
    float o0 = 0.f, o1 = 0.f;
    #pragma unroll
    for (int k = 0; k <= HOPS; ++k) {
        const unsigned g = hbuf[(size_t)k * n * 32 + (size_t)node * 32 + sl];
        const float lo = bflo(g), hi = bfhi(g);
        float tv = lo * sv.x + hi * sv.y;
        #pragma unroll
        for (int off = 16; off > 0; off >>= 1) tv += __shfl_xor(tv, off, 32);
        const float sg = 1.f / (1.f + expf(-tv));
        o0 = fmaf(sg, lo, o0);
        o1 = fmaf(sg, hi, o1);
    }
    float2 ov; ov.x = o0; ov.y = o1;
    ((float2*)out)[(size_t)node * 32 + sl] = ov;
}

// ---------------------------------------------------------------------------
extern "C" void kernel_launch(void* const* d_in, const int* in_sizes, int n_in,
                              void* d_out, int out_size, void* d_ws, size_t ws_size,
                              hipStream_t stream)
{
    const float* x  = (const float*)d_in[0];
    const int*   er = (const int*)  d_in[1];
    const int*   ec = (const int*)  d_in[2];
    const float* ev = (const float*)d_in[3];
    const float* W1 = (const float*)d_in[4];
    const float* b1 = (const float*)d_in[5];
    const float* W2 = (const float*)d_in[6];
    const float* b2 = (const float*)d_in[7];
    const float* s  = (const float*)d_in[8];
    float* out = (float*)d_out;

    const int n = in_sizes[0] / NIN;   // 100000
    const int e = in_sizes[1];         // 1600000

    // workspace carve (256B aligned): ~160 MB of ~800 MB ws
    char* w = (char*)d_ws;
    auto carve = [&](size_t bytes) { char* p = w; w += (bytes + 255) & ~(size_t)255; return p; };
    unsigned* hbuf   = (unsigned*)carve((size_t)(HOPS + 1) * n * 32 * 4);  // 140.8 MB
    int*      deg    = (int*)     carve((size_t)n * 4);
    int*      rp     = (int*)     carve(((size_t)n + 1) * 4);
    int*      cur    = (int*)     carve((size_t)n * 4);
    unsigned long long* cpack = (unsigned long long*)carve((size_t)e * 8); // 12.8 MB
    int*      bsum   = (int*)     carve(1024 * 4);
    unsigned short* W1f = (unsigned short*)carve((size_t)NHID * NIN * 2);
    unsigned short* W2f = (unsigned short*)carve((size_t)NOUT * NHID * 2);

    hipMemsetAsync(deg, 0, (size_t)n * 4, stream);

    k_preconv<<<(NHID * NIN + 255) / 256, 256, 0, stream>>>(W1, W2, W1f, W2f);

    const int mgrid = (n + 63) / 64;
    mlp_kernel<<<mgrid, 256, 0, stream>>>(x, W1f, b1, W2f, b2, hbuf, n);

    const int eg = (e + 255) / 256;
    const int nb = (n + 255) / 256;
    k_count  <<<eg, 256, 0, stream>>>(er, deg, e);
    k_scan1  <<<nb, 256, 0, stream>>>(deg, rp, bsum, n);
    k_scan2  <<<1, 512, 0, stream>>>(bsum, nb);
    k_scan3  <<<nb, 256, 0, stream>>>(rp, cur, bsum, n, e);
    k_scatter<<<eg, 256, 0, stream>>>(er, ec, ev, cur, cpack, e);

    const int hgrid = ((size_t)n * 32 + 255) / 256;
    for (int hop = 0; hop < HOPS; ++hop) {
        hop_kernel<<<hgrid, 256, 0, stream>>>(
            hbuf + (size_t)hop * n * 32, hbuf + (size_t)(hop + 1) * n * 32,
            rp, cpack, n);
    }

    k_combine<<<hgrid, 256, 0, stream>>>(hbuf, s, out, n);
}

// Round 8
// 629.267 us; speedup vs baseline: 1.3455x; 1.0027x over previous
//
#include <hip/hip_runtime.h>
#include <hip/hip_bf16.h>

#define NIN  512
#define NHID 256
#define NOUT 64
#define HOPS 10
#define NSLICE 8

typedef __attribute__((ext_vector_type(8))) short bf16x8;
typedef __attribute__((ext_vector_type(4))) float f32x4;

__device__ __forceinline__ unsigned short f2bf(float f) {
    unsigned u = __float_as_uint(f);
    u += 0x7FFFu + ((u >> 16) & 1u);            // RNE
    return (unsigned short)(u >> 16);
}
__device__ __forceinline__ unsigned pk2(float a, float b) {
    return (unsigned)f2bf(a) | ((unsigned)f2bf(b) << 16);
}
__device__ __forceinline__ float bflo(unsigned g) { return __uint_as_float(g << 16); }
__device__ __forceinline__ float bfhi(unsigned g) { return __uint_as_float(g & 0xFFFF0000u); }

// ---------------------------------------------------------------------------
// Pre-permute W1, W2 into MFMA A-fragment order (bf16).  (verified R4/R5)
// ---------------------------------------------------------------------------
__global__ void k_preconv(const float* __restrict__ W1, const float* __restrict__ W2,
                          unsigned short* __restrict__ W1f, unsigned short* __restrict__ W2f)
{
    const int i = blockIdx.x * 256 + threadIdx.x;
    if (i < NHID * NIN) {
        const int j = i & 7, l = (i >> 3) & 63, fi = i >> 9;
        const int ks = fi >> 4, w = (fi >> 2) & 3, nf = fi & 3;
        const int col = w * 64 + nf * 16 + (l & 15);
        const int k   = ks * 32 + ((l >> 4) << 3) + j;
        W1f[i] = f2bf(W1[col * NIN + k]);
    }
    if (i < NOUT * NHID) {
        const int j = i & 7, l = (i >> 3) & 63, fi = i >> 9;
        const int ks = fi >> 2, nf = fi & 3;
        const int col = nf * 16 + (l & 15);
        const int k   = ks * 32 + ((j >> 2) << 4) + ((l >> 4) << 2) + (j & 3);
        W2f[i] = f2bf(W2[col * NHID + k]);
    }
}

// ---------------------------------------------------------------------------
// Fused MFMA MLP (operand-swapped, verified R4/R5/R7). Outputs bf16-packed h0.
// GEMM1 x-loads issued 2 k-tiles ahead (pair-unrolled, named register slots).
// ---------------------------------------------------------------------------
__global__ __launch_bounds__(256, 3) void mlp_kernel(
    const float* __restrict__ x, const unsigned short* __restrict__ W1f,
    const float* __restrict__ b1, const unsigned short* __restrict__ W2f,
    const float* __restrict__ b2,
    unsigned* __restrict__ hpack, int n)
{
    // LDS overlay: [0,32768)        B2L [4][8][64][8] h1^T frags (GEMM2 phase)
    //              [32768, +8192)   BX  [2][4][64][8] x frags (GEMM1 dbuf)
    //              [32768, +17408)  H0L [64][68] f32 (epilogue, after BX dead)
    __shared__ __align__(16) char smem[50176];
    short* B2L  = (short*)smem;
    short* BX   = (short*)(smem + 32768);
    float* H0L  = (float*)(smem + 32768);

    const int t  = threadIdx.x;
    const int w  = t >> 6, lz = t & 63;
    const int row0 = blockIdx.x * 64;

    const int srow = t >> 2;
    int xrow = row0 + srow; if (xrow >= n) xrow = n - 1;
    const float4* xp = (const float4*)(x + (size_t)xrow * NIN);
    const int q4a = t & 3, q4b = (t & 3) + 4;

    f32x4 acc[4][4];
    #pragma unroll
    for (int a = 0; a < 4; ++a)
        #pragma unroll
        for (int b = 0; b < 4; ++b) acc[a][b] = (f32x4)(0.f);

    auto xwrite = [&](int b, float4 va, float4 vb) {
        unsigned long long pa = (unsigned long long)pk2(va.x, va.y)
                              | ((unsigned long long)pk2(va.z, va.w) << 32);
        unsigned long long pb = (unsigned long long)pk2(vb.x, vb.y)
                              | ((unsigned long long)pk2(vb.z, vb.w) << 32);
        *(unsigned long long*)&BX[(((((b << 2) + (srow >> 4)) << 6)
            + ((srow & 15) | ((q4a >> 1) << 4))) << 3) + ((q4a & 1) << 2)] = pa;
        *(unsigned long long*)&BX[(((((b << 2) + (srow >> 4)) << 6)
            + ((srow & 15) | ((q4b >> 1) << 4))) << 3) + ((q4b & 1) << 2)] = pb;
    };
    auto wload = [&](int kt, bf16x8* wf) {
        const unsigned short* wp = W1f + ((size_t)kt << 13) + (w << 11) + (lz << 3);
        #pragma unroll
        for (int hf = 0; hf < 4; ++hf)
            wf[hf] = *(const bf16x8*)(wp + (hf << 9));   // coalesced, L2-resident
    };
    auto compute = [&](int b, const bf16x8* wf) {
        bf16x8 xf[4];
        #pragma unroll
        for (int nfn = 0; nfn < 4; ++nfn)
            xf[nfn] = *(const bf16x8*)&BX[((((b << 2) + nfn) << 6) + lz) << 3];
        #pragma unroll
        for (int nfn = 0; nfn < 4; ++nfn)
            #pragma unroll
            for (int hf = 0; hf < 4; ++hf)
                acc[nfn][hf] = __builtin_amdgcn_mfma_f32_16x16x32_bf16(
                    wf[hf], xf[nfn], acc[nfn][hf], 0, 0, 0);   // A=W1, B=x^T
    };

    bf16x8 wfc[4], wfn[4];
    float4 sAa, sAb, sBa, sBb;   // two in-flight x tiles (named slots, rule #20)
    {
        float4 xa = xp[q4a], xb = xp[q4b];
        wload(0, wfc);
        xwrite(0, xa, xb);
        sAa = xp[8 + q4a]; sAb = xp[8 + q4b];      // tile kt=1 issued early
    }
    __syncthreads();

    #pragma unroll 1
    for (int kt = 0; kt < 16; kt += 2) {
        // ---- even sub-iter: compute tile kt (buffer 0) -------------------
        if (kt + 2 < 16) { sBa = xp[((kt + 2) << 3) + q4a]; sBb = xp[((kt + 2) << 3) + q4b]; }
        wload(kt + 1, wfn);
        compute(0, wfc);
        xwrite(1, sAa, sAb);                       // tile kt+1 (kt+1 <= 15 always)
        __syncthreads();
        // ---- odd sub-iter: compute tile kt+1 (buffer 1) ------------------
        if (kt + 3 < 16) { sAa = xp[((kt + 3) << 3) + q4a]; sAb = xp[((kt + 3) << 3) + q4b]; }
        if (kt + 2 < 16) wload(kt + 2, wfc);
        compute(1, wfn);
        if (kt + 2 < 16) xwrite(0, sBa, sBb);      // tile kt+2
        __syncthreads();
    }

    // ---- bias + relu + in-register repack -> B2L (h1^T B-fragments) -----
    {
        float4 b1q[4];
        #pragma unroll
        for (int hf = 0; hf < 4; ++hf)
            b1q[hf] = *(const float4*)(b1 + (w << 6) + (hf << 4) + ((lz >> 4) << 2));
        #pragma unroll
        for (int nfn = 0; nfn < 4; ++nfn) {
            #pragma unroll
            for (int cl = 0; cl < 2; ++cl) {
                f32x4 a0 = acc[nfn][2 * cl], a1 = acc[nfn][2 * cl + 1];
                float4 c0 = b1q[2 * cl], c1 = b1q[2 * cl + 1];
                uint4 pv;
                pv.x = pk2(fmaxf(a0.x + c0.x, 0.f), fmaxf(a0.y + c0.y, 0.f));
                pv.y = pk2(fmaxf(a0.z + c0.z, 0.f), fmaxf(a0.w + c0.w, 0.f));
                pv.z = pk2(fmaxf(a1.x + c1.x, 0.f), fmaxf(a1.y + c1.y, 0.f));
                pv.w = pk2(fmaxf(a1.z + c1.z, 0.f), fmaxf(a1.w + c1.w, 0.f));
                *(uint4*)&B2L[((((nfn << 3) + (w << 1) + cl) << 6) + lz) << 3] = pv;
            }
        }
    }
    __syncthreads();

    // ---- GEMM2: h0^T = W2 @ h1^T ----------------------------------------
    f32x4 acc2[4];
    #pragma unroll
    for (int nf2 = 0; nf2 < 4; ++nf2) acc2[nf2] = (f32x4)(0.f);

    #pragma unroll
    for (int c = 0; c < 8; ++c) {
        bf16x8 hfrag = *(const bf16x8*)&B2L[((((w << 3) + c) << 6) + lz) << 3];
        #pragma unroll
        for (int nf2 = 0; nf2 < 4; ++nf2) {
            bf16x8 wfrag = *(const bf16x8*)(W2f + (((c << 2) + nf2) << 9) + (lz << 3));
            acc2[nf2] = __builtin_amdgcn_mfma_f32_16x16x32_bf16(
                wfrag, hfrag, acc2[nf2], 0, 0, 0);
        }
    }

    // ---- epilogue: bias, LDS reshape, packed stores ----------------------
    {
        const int mloc = (w << 4) + (lz & 15);
        #pragma unroll
        for (int nf2 = 0; nf2 < 4; ++nf2) {
            float4 bq = *(const float4*)(b2 + (nf2 << 4) + ((lz >> 4) << 2));
            float4 hv;
            hv.x = acc2[nf2].x + bq.x; hv.y = acc2[nf2].y + bq.y;
            hv.z = acc2[nf2].z + bq.z; hv.w = acc2[nf2].w + bq.w;
            *(float4*)&H0L[mloc * 68 + (nf2 << 4) + ((lz >> 4) << 2)] = hv;
        }
    }
    __syncthreads();

    {
        const int m = t >> 2, q = t & 3;
        const int g = row0 + m;
        if (g < n) {
            unsigned* hp = hpack + (size_t)g * 32 + (q << 3);
            #pragma unroll
            for (int i = 0; i < 16; i += 4) {
                float4 hv = *(const float4*)&H0L[m * 68 + (q << 4) + i];
                uint2 pv;
                pv.x = pk2(hv.x, hv.y);
                pv.y = pk2(hv.z, hv.w);
                *(uint2*)(hp + (i >> 1)) = pv;
            }
        }
    }
}

// ---------------------------------------------------------------------------
// CSR build: degree count -> hierarchical exclusive scan -> sliced scatter
// ---------------------------------------------------------------------------
__global__ void k_count(const int* __restrict__ erow, int* __restrict__ deg, int e) {
    int i = blockIdx.x * 256 + threadIdx.x;
    if (i < e) atomicAdd(&deg[erow[i]], 1);
}

__global__ void k_scan1(const int* __restrict__ deg, int* __restrict__ rp,
                        int* __restrict__ bsum, int nv) {
    __shared__ int sm[256];
    const int i = blockIdx.x * 256 + threadIdx.x;
    const int v = (i < nv) ? deg[i] : 0;
    sm[threadIdx.x] = v;
    __syncthreads();
    for (int off = 1; off < 256; off <<= 1) {
        int tv = (threadIdx.x >= off) ? sm[threadIdx.x - off] : 0;
        __syncthreads();
        sm[threadIdx.x] += tv;
        __syncthreads();
    }
    if (i < nv) rp[i] = sm[threadIdx.x] - v;
    if (threadIdx.x == 255) bsum[blockIdx.x] = sm[255];
}

__global__ void k_scan2(int* __restrict__ bsum, int nb) {
    __shared__ int sm[512];
    const int tid = threadIdx.x;
    const int v = (tid < nb) ? bsum[tid] : 0;
    sm[tid] = v;
    __syncthreads();
    for (int off = 1; off < 512; off <<= 1) {
        int tv = (tid >= off) ? sm[tid - off] : 0;
        __syncthreads();
        sm[tid] += tv;
        __syncthreads();
    }
    if (tid < nb) bsum[tid] = sm[tid] - v;
}

__global__ void k_scan3(int* __restrict__ rp, int* __restrict__ cur,
                        const int* __restrict__ bsum, int nv, int e) {
    const int i = blockIdx.x * 256 + threadIdx.x;
    if (i < nv) {
        const int vv = rp[i] + bsum[blockIdx.x];
        rp[i]  = vv;
        cur[i] = vv;
    }
    if (i == 0) rp[nv] = e;
}

// Sliced scatter: only rows in [lo,hi) -> destination window ~1.6MB, fits
// per-XCD L2 so write-allocate churn stays in-cache.
__global__ void k_scatter_slice(const int* __restrict__ erow, const int* __restrict__ ecol,
                                const float* __restrict__ ev, int* __restrict__ cur,
                                unsigned long long* __restrict__ cpack, int e,
                                int lo, int hi) {
    const int i = blockIdx.x * 256 + threadIdx.x;
    if (i < e) {
        const int r = erow[i];
        if (r >= lo && r < hi) {
            const int p = atomicAdd(&cur[r], 1);
            cpack[p] = ((unsigned long long)__float_as_uint(ev[i]) << 32)
                     | (unsigned)ecol[i];
        }
    }
}

// ---------------------------------------------------------------------------
// One propagation hop (pull, CSR, bf16-packed h). Pure SpMM; sig deferred.
// 32 lanes = 1 node (2 features/lane).
// ---------------------------------------------------------------------------
__global__ __launch_bounds__(256) void hop_kernel(
    const unsigned* __restrict__ h_in, unsigned* __restrict__ h_out,
    const int* __restrict__ row_ptr, const unsigned long long* __restrict__ cpack,
    int n)
{
    const int t  = threadIdx.x;
    const int sl = t & 31;
    const int node = (blockIdx.x * 256 + t) >> 5;
    if (node >= n) return;
    const int start = row_ptr[node];
    const int end   = row_ptr[node + 1];
    float a0 = 0.f, a1 = 0.f;
    for (int base = start; base < end; base += 32) {
        const int idx = base + sl;
        unsigned long long pc = (idx < end) ? cpack[idx] : 0ULL;
        int   c = (int)(unsigned)pc;
        float v = __uint_as_float((unsigned)(pc >> 32));
        const int cnt = min(32, end - base);
        int e = 0;
        for (; e + 4 <= cnt; e += 4) {           // 4 gathers in flight
            int   c0 = __shfl(c, e, 32),     c1 = __shfl(c, e + 1, 32);
            int   c2 = __shfl(c, e + 2, 32), c3 = __shfl(c, e + 3, 32);
            float v0 = __shfl(v, e, 32),     v1 = __shfl(v, e + 1, 32);
            float v2 = __shfl(v, e + 2, 32), v3 = __shfl(v, e + 3, 32);
            unsigned g0 = h_in[(size_t)c0 * 32 + sl];
            unsigned g1 = h_in[(size_t)c1 * 32 + sl];
            unsigned g2 = h_in[(size_t)c2 * 32 + sl];
            unsigned g3 = h_in[(size_t)c3 * 32 + sl];
            a0 = fmaf(v0, bflo(g0), a0); a1 = fmaf(v0, bfhi(g0), a1);
            a0 = fmaf(v1, bflo(g1), a0); a1 = fmaf(v1, bfhi(g1), a1);
            a0 = fmaf(v2, bflo(g2), a0); a1 = fmaf(v2, bfhi(g2), a1);
            a0 = fmaf(v3, bflo(g3), a0); a1 = fmaf(v3, bfhi(g3), a1);
        }
        for (; e < cnt; ++e) {
            int   cc = __shfl(c, e, 32);
            float vv = __shfl(v, e, 32);
            unsigned g = h_in[(size_t)cc * 32 + sl];
            a0 = fmaf(vv, bflo(g), a0); a1 = fmaf(vv, bfhi(g), a1);
        }
    }
    h_out[(size_t)node * 32 + sl] = pk2(a0, a1);
}

// ---------------------------------------------------------------------------
// Final combine: sig_k(n) = sigmoid(h_k(n).s); out = sum_k sig_k(n) h_k(n)
// ---------------------------------------------------------------------------
__global__ __launch_bounds__(256) void k_combine(
    const unsigned* __restrict__ hbuf, const float* __restrict__ s,
    float* __restrict__ out, int n)
{
    const int gid  = blockIdx.x * 256 + threadIdx.x;
    const int node = gid >> 5, sl = gid & 31;
    if (node >= n) return;
    const float2 sv = ((const float2*)s)[sl];
    float o0 = 0.f, o1 = 0.f;
    #pragma unroll
    for (int k = 0; k <= HOPS; ++k) {
        const unsigned g = hbuf[(size_t)k * n * 32 + (size_t)node * 32 + sl];
        const float lo = bflo(g), hi = bfhi(g);
        float tv = lo * sv.x + hi * sv.y;
        #pragma unroll
        for (int off = 16; off > 0; off >>= 1) tv += __shfl_xor(tv, off, 32);
        const float sg = 1.f / (1.f + expf(-tv));
        o0 = fmaf(sg, lo, o0);
        o1 = fmaf(sg, hi, o1);
    }
    float2 ov; ov.x = o0; ov.y = o1;
    ((float2*)out)[(size_t)node * 32 + sl] = ov;
}

// ---------------------------------------------------------------------------
extern "C" void kernel_launch(void* const* d_in, const int* in_sizes, int n_in,
                              void* d_out, int out_size, void* d_ws, size_t ws_size,
                              hipStream_t stream)
{
    const float* x  = (const float*)d_in[0];
    const int*   er = (const int*)  d_in[1];
    const int*   ec = (const int*)  d_in[2];
    const float* ev = (const float*)d_in[3];
    const float* W1 = (const float*)d_in[4];
    const float* b1 = (const float*)d_in[5];
    const float* W2 = (const float*)d_in[6];
    const float* b2 = (const float*)d_in[7];
    const float* s  = (const float*)d_in[8];
    float* out = (float*)d_out;

    const int n = in_sizes[0] / NIN;   // 100000
    const int e = in_sizes[1];         // 1600000

    // workspace carve (256B aligned): ~160 MB of ~800 MB ws
    char* w = (char*)d_ws;
    auto carve = [&](size_t bytes) { char* p = w; w += (bytes + 255) & ~(size_t)255; return p; };
    unsigned* hbuf   = (unsigned*)carve((size_t)(HOPS + 1) * n * 32 * 4);  // 140.8 MB
    int*      deg    = (int*)     carve((size_t)n * 4);
    int*      rp     = (int*)     carve(((size_t)n + 1) * 4);
    int*      cur    = (int*)     carve((size_t)n * 4);
    unsigned long long* cpack = (unsigned long long*)carve((size_t)e * 8); // 12.8 MB
    int*      bsum   = (int*)     carve(1024 * 4);
    unsigned short* W1f = (unsigned short*)carve((size_t)NHID * NIN * 2);
    unsigned short* W2f = (unsigned short*)carve((size_t)NOUT * NHID * 2);

    hipMemsetAsync(deg, 0, (size_t)n * 4, stream);

    k_preconv<<<(NHID * NIN + 255) / 256, 256, 0, stream>>>(W1, W2, W1f, W2f);

    const int mgrid = (n + 63) / 64;
    mlp_kernel<<<mgrid, 256, 0, stream>>>(x, W1f, b1, W2f, b2, hbuf, n);

    const int eg = (e + 255) / 256;
    const int nb = (n + 255) / 256;
    k_count<<<eg, 256, 0, stream>>>(er, deg, e);
    k_scan1<<<nb, 256, 0, stream>>>(deg, rp, bsum, n);
    k_scan2<<<1, 512, 0, stream>>>(bsum, nb);
    k_scan3<<<nb, 256, 0, stream>>>(rp, cur, bsum, n, e);

    const int sd = (n + NSLICE - 1) / NSLICE;
    for (int p = 0; p < NSLICE; ++p) {
        const int lo = p * sd;
        const int hi = (lo + sd < n) ? lo + sd : n;
        if (lo >= n) break;
        k_scatter_slice<<<eg, 256, 0, stream>>>(er, ec, ev, cur, cpack, e, lo, hi);
    }

    const int hgrid = ((size_t)n * 32 + 255) / 256;
    for (int hop = 0; hop < HOPS; ++hop) {
        hop_kernel<<<hgrid, 256, 0, stream>>>(
            hbuf + (size_t)hop * n * 32, hbuf + (size_t)(hop + 1) * n * 32,
            rp, cpack, n);
    }

    k_combine<<<hgrid, 256, 0, stream>>>(hbuf, s, out, n);
}

// Round 9
// 528.416 us; speedup vs baseline: 1.6023x; 1.1909x over previous
//
#include <hip/hip_runtime.h>
#include <hip/hip_bf16.h>

#define NIN  512
#define NHID 256
#define NOUT 64
#define HOPS 10

typedef __attribute__((ext_vector_type(8))) short bf16x8;
typedef __attribute__((ext_vector_type(4))) float f32x4;

__device__ __forceinline__ unsigned short f2bf(float f) {
    unsigned u = __float_as_uint(f);
    u += 0x7FFFu + ((u >> 16) & 1u);            // RNE
    return (unsigned short)(u >> 16);
}
__device__ __forceinline__ unsigned pk2(float a, float b) {
    return (unsigned)f2bf(a) | ((unsigned)f2bf(b) << 16);
}
__device__ __forceinline__ float bflo(unsigned g) { return __uint_as_float(g << 16); }
__device__ __forceinline__ float bfhi(unsigned g) { return __uint_as_float(g & 0xFFFF0000u); }

// ---------------------------------------------------------------------------
// Pre-permute W1, W2 into MFMA A-fragment order (bf16).  (verified R4/R5)
// ---------------------------------------------------------------------------
__global__ void k_preconv(const float* __restrict__ W1, const float* __restrict__ W2,
                          unsigned short* __restrict__ W1f, unsigned short* __restrict__ W2f)
{
    const int i = blockIdx.x * 256 + threadIdx.x;
    if (i < NHID * NIN) {
        const int j = i & 7, l = (i >> 3) & 63, fi = i >> 9;
        const int ks = fi >> 4, w = (fi >> 2) & 3, nf = fi & 3;
        const int col = w * 64 + nf * 16 + (l & 15);
        const int k   = ks * 32 + ((l >> 4) << 3) + j;
        W1f[i] = f2bf(W1[col * NIN + k]);
    }
    if (i < NOUT * NHID) {
        const int j = i & 7, l = (i >> 3) & 63, fi = i >> 9;
        const int ks = fi >> 2, nf = fi & 3;
        const int col = nf * 16 + (l & 15);
        const int k   = ks * 32 + ((j >> 2) << 4) + ((l >> 4) << 2) + (j & 3);
        W2f[i] = f2bf(W2[col * NHID + k]);
    }
}

// ---------------------------------------------------------------------------
// Fused MFMA MLP (operand-swapped, verified R4-R8). Outputs bf16-packed h0.
// ---------------------------------------------------------------------------
__global__ __launch_bounds__(256, 3) void mlp_kernel(
    const float* __restrict__ x, const unsigned short* __restrict__ W1f,
    const float* __restrict__ b1, const unsigned short* __restrict__ W2f,
    const float* __restrict__ b2,
    unsigned* __restrict__ hpack, int n)
{
    __shared__ __align__(16) char smem[50176];
    short* B2L  = (short*)smem;
    short* BX   = (short*)(smem + 32768);
    float* H0L  = (float*)(smem + 32768);

    const int t  = threadIdx.x;
    const int w  = t >> 6, lz = t & 63;
    const int row0 = blockIdx.x * 64;

    const int srow = t >> 2;
    int xrow = row0 + srow; if (xrow >= n) xrow = n - 1;
    const float4* xp = (const float4*)(x + (size_t)xrow * NIN);
    const int q4a = t & 3, q4b = (t & 3) + 4;

    f32x4 acc[4][4];
    #pragma unroll
    for (int a = 0; a < 4; ++a)
        #pragma unroll
        for (int b = 0; b < 4; ++b) acc[a][b] = (f32x4)(0.f);

    auto xwrite = [&](int b, float4 va, float4 vb) {
        unsigned long long pa = (unsigned long long)pk2(va.x, va.y)
                              | ((unsigned long long)pk2(va.z, va.w) << 32);
        unsigned long long pb = (unsigned long long)pk2(vb.x, vb.y)
                              | ((unsigned long long)pk2(vb.z, vb.w) << 32);
        *(unsigned long long*)&BX[(((((b << 2) + (srow >> 4)) << 6)
            + ((srow & 15) | ((q4a >> 1) << 4))) << 3) + ((q4a & 1) << 2)] = pa;
        *(unsigned long long*)&BX[(((((b << 2) + (srow >> 4)) << 6)
            + ((srow & 15) | ((q4b >> 1) << 4))) << 3) + ((q4b & 1) << 2)] = pb;
    };
    auto wload = [&](int kt, bf16x8* wf) {
        const unsigned short* wp = W1f + ((size_t)kt << 13) + (w << 11) + (lz << 3);
        #pragma unroll
        for (int hf = 0; hf < 4; ++hf)
            wf[hf] = *(const bf16x8*)(wp + (hf << 9));
    };
    auto compute = [&](int b, const bf16x8* wf) {
        bf16x8 xf[4];
        #pragma unroll
        for (int nfn = 0; nfn < 4; ++nfn)
            xf[nfn] = *(const bf16x8*)&BX[((((b << 2) + nfn) << 6) + lz) << 3];
        #pragma unroll
        for (int nfn = 0; nfn < 4; ++nfn)
            #pragma unroll
            for (int hf = 0; hf < 4; ++hf)
                acc[nfn][hf] = __builtin_amdgcn_mfma_f32_16x16x32_bf16(
                    wf[hf], xf[nfn], acc[nfn][hf], 0, 0, 0);
    };

    bf16x8 wfc[4], wfn[4];
    float4 sAa, sAb, sBa, sBb;
    {
        float4 xa = xp[q4a], xb = xp[q4b];
        wload(0, wfc);
        xwrite(0, xa, xb);
        sAa = xp[8 + q4a]; sAb = xp[8 + q4b];
    }
    __syncthreads();

    #pragma unroll 1
    for (int kt = 0; kt < 16; kt += 2) {
        if (kt + 2 < 16) { sBa = xp[((kt + 2) << 3) + q4a]; sBb = xp[((kt + 2) << 3) + q4b]; }
        wload(kt + 1, wfn);
        compute(0, wfc);
        xwrite(1, sAa, sAb);
        __syncthreads();
        if (kt + 3 < 16) { sAa = xp[((kt + 3) << 3) + q4a]; sAb = xp[((kt + 3) << 3) + q4b]; }
        if (kt + 2 < 16) wload(kt + 2, wfc);
        compute(1, wfn);
        if (kt + 2 < 16) xwrite(0, sBa, sBb);
        __syncthreads();
    }

    {
        float4 b1q[4];
        #pragma unroll
        for (int hf = 0; hf < 4; ++hf)
            b1q[hf] = *(const float4*)(b1 + (w << 6) + (hf << 4) + ((lz >> 4) << 2));
        #pragma unroll
        for (int nfn = 0; nfn < 4; ++nfn) {
            #pragma unroll
            for (int cl = 0; cl < 2; ++cl) {
                f32x4 a0 = acc[nfn][2 * cl], a1 = acc[nfn][2 * cl + 1];
                float4 c0 = b1q[2 * cl], c1 = b1q[2 * cl + 1];
                uint4 pv;
                pv.x = pk2(fmaxf(a0.x + c0.x, 0.f), fmaxf(a0.y + c0.y, 0.f));
                pv.y = pk2(fmaxf(a0.z + c0.z, 0.f), fmaxf(a0.w + c0.w, 0.f));
                pv.z = pk2(fmaxf(a1.x + c1.x, 0.f), fmaxf(a1.y + c1.y, 0.f));
                pv.w = pk2(fmaxf(a1.z + c1.z, 0.f), fmaxf(a1.w + c1.w, 0.f));
                *(uint4*)&B2L[((((nfn << 3) + (w << 1) + cl) << 6) + lz) << 3] = pv;
            }
        }
    }
    __syncthreads();

    f32x4 acc2[4];
    #pragma unroll
    for (int nf2 = 0; nf2 < 4; ++nf2) acc2[nf2] = (f32x4)(0.f);

    #pragma unroll
    for (int c = 0; c < 8; ++c) {
        bf16x8 hfrag = *(const bf16x8*)&B2L[((((w << 3) + c) << 6) + lz) << 3];
        #pragma unroll
        for (int nf2 = 0; nf2 < 4; ++nf2) {
            bf16x8 wfrag = *(const bf16x8*)(W2f + (((c << 2) + nf2) << 9) + (lz << 3));
            acc2[nf2] = __builtin_amdgcn_mfma_f32_16x16x32_bf16(
                wfrag, hfrag, acc2[nf2], 0, 0, 0);
        }
    }

    {
        const int mloc = (w << 4) + (lz & 15);
        #pragma unroll
        for (int nf2 = 0; nf2 < 4; ++nf2) {
            float4 bq = *(const float4*)(b2 + (nf2 << 4) + ((lz >> 4) << 2));
            float4 hv;
            hv.x = acc2[nf2].x + bq.x; hv.y = acc2[nf2].y + bq.y;
            hv.z = acc2[nf2].z + bq.z; hv.w = acc2[nf2].w + bq.w;
            *(float4*)&H0L[mloc * 68 + (nf2 << 4) + ((lz >> 4) << 2)] = hv;
        }
    }
    __syncthreads();

    {
        const int m = t >> 2, q = t & 3;
        const int g = row0 + m;
        if (g < n) {
            unsigned* hp = hpack + (size_t)g * 32 + (q << 3);
            #pragma unroll
            for (int i = 0; i < 16; i += 4) {
                float4 hv = *(const float4*)&H0L[m * 68 + (q << 4) + i];
                uint2 pv;
                pv.x = pk2(hv.x, hv.y);
                pv.y = pk2(hv.z, hv.w);
                *(uint2*)(hp + (i >> 1)) = pv;
            }
        }
    }
}

// ---------------------------------------------------------------------------
// CSR build via single-digit bucket sort (bucket = row >> 8, 256 rows each).
// NO 1.6M-scale global atomics anywhere.
// ---------------------------------------------------------------------------

// (1) bucket histogram: LDS hist + one flush atomic per (block,bucket)
__global__ __launch_bounds__(256) void kA_hist(
    const int* __restrict__ erow, int* __restrict__ bcnt, int e, int nbk)
{
    __shared__ int lh[512];
    const int t = threadIdx.x;
    for (int b = t; b < 512; b += 256) lh[b] = 0;
    __syncthreads();
    for (int i = blockIdx.x * 256 + t; i < e; i += gridDim.x * 256)
        atomicAdd(&lh[erow[i] >> 8], 1);
    __syncthreads();
    for (int b = t; b < nbk; b += 256)
        if (lh[b]) atomicAdd(&bcnt[b], lh[b]);
}

// (2) exclusive scan of bucket counts (1 block); seeds padded cursors
__global__ __launch_bounds__(512) void kB_scan(
    const int* __restrict__ bcnt, int* __restrict__ bbase,
    int* __restrict__ gcur, int e, int nbk)
{
    __shared__ int sm[512];
    const int tid = threadIdx.x;
    const int v = (tid < nbk) ? bcnt[tid] : 0;
    sm[tid] = v;
    __syncthreads();
    for (int off = 1; off < 512; off <<= 1) {
        int tv = (tid >= off) ? sm[tid - off] : 0;
        __syncthreads();
        sm[tid] += tv;
        __syncthreads();
    }
    if (tid < nbk) {
        const int base = sm[tid] - v;
        bbase[tid] = base;
        gcur[tid * 16] = base;        // 64B-padded cursor: one counter per line
    }
    if (tid == 0) bbase[nbk] = e;
}

// (3) bucket-grouped append: block claims per-bucket windows, LDS-ranks within
__global__ __launch_bounds__(256) void k_bapp(
    const int* __restrict__ erow, const int* __restrict__ ecol,
    const float* __restrict__ ev, int* __restrict__ gcur,
    uint4* __restrict__ brec, int e, int nbk)
{
    __shared__ int lh[512];
    __shared__ int lbase[512];
    const int t = threadIdx.x;
    const int c0 = blockIdx.x * 4096;
    for (int b = t; b < 512; b += 256) lh[b] = 0;
    __syncthreads();
    int rr[16];
    #pragma unroll
    for (int j = 0; j < 16; ++j) {
        const int i = c0 + j * 256 + t;
        rr[j] = (i < e) ? erow[i] : -1;
        if (rr[j] >= 0) atomicAdd(&lh[rr[j] >> 8], 1);
    }
    __syncthreads();
    for (int b = t; b < nbk; b += 256) {
        const int c = lh[b];
        lbase[b] = c ? atomicAdd(&gcur[b * 16], c) : 0;
        lh[b] = 0;                     // reuse as rank counter
    }
    __syncthreads();
    #pragma unroll
    for (int j = 0; j < 16; ++j) {
        const int i = c0 + j * 256 + t;
        if (rr[j] >= 0) {
            const int b  = rr[j] >> 8;
            const int rk = atomicAdd(&lh[b], 1);
            uint4 rec;
            rec.x = (unsigned)rr[j];
            rec.y = (unsigned)ecol[i];
            rec.z = __float_as_uint(ev[i]);
            rec.w = 0;
            brec[lbase[b] + rk] = rec;
        }
    }
}

// (4) per-bucket row counts -> block-local scan -> rp (no global scan chain)
__global__ __launch_bounds__(256) void k_brow(
    const uint4* __restrict__ brec, const int* __restrict__ bbase,
    int* __restrict__ rp, int n, int e)
{
    __shared__ int rc[256];
    __shared__ int sc[256];
    const int b = blockIdx.x, t = threadIdx.x;
    const int lo = bbase[b], hi = bbase[b + 1];
    rc[t] = 0;
    __syncthreads();
    for (int i = lo + t; i < hi; i += 256) {
        const unsigned r = ((const unsigned*)brec)[(size_t)i * 4];   // .x
        atomicAdd(&rc[r & 255], 1);
    }
    __syncthreads();
    const int v = rc[t];
    sc[t] = v;
    __syncthreads();
    for (int off = 1; off < 256; off <<= 1) {
        int tv = (t >= off) ? sc[t - off] : 0;
        __syncthreads();
        sc[t] += tv;
        __syncthreads();
    }
    const int row = (b << 8) + t;
    if (row < n) rp[row] = lo + sc[t] - v;
    if (b == 0 && t == 0) rp[n] = e;
}

// (5) final in-bucket scatter: LDS ranks, contiguous ~32KB dest window
__global__ __launch_bounds__(256) void k_bwrite(
    const uint4* __restrict__ brec, const int* __restrict__ bbase,
    const int* __restrict__ rp, unsigned long long* __restrict__ cpack)
{
    __shared__ int rc[256];
    const int b = blockIdx.x, t = threadIdx.x;
    const int lo = bbase[b], hi = bbase[b + 1];
    rc[t] = 0;
    __syncthreads();
    for (int i = lo + t; i < hi; i += 256) {
        const uint4 rec = brec[i];
        const int rk = atomicAdd(&rc[rec.x & 255], 1);
        cpack[rp[rec.x] + rk] = ((unsigned long long)rec.z << 32) | rec.y;
    }
}

// ---------------------------------------------------------------------------
// One propagation hop (pull, CSR, bf16-packed h). Pure SpMM; sig deferred.
// ---------------------------------------------------------------------------
__global__ __launch_bounds__(256) void hop_kernel(
    const unsigned* __restrict__ h_in, unsigned* __restrict__ h_out,
    const int* __restrict__ row_ptr, const unsigned long long* __restrict__ cpack,
    int n)
{
    const int t  = threadIdx.x;
    const int sl = t & 31;
    const int node = (blockIdx.x * 256 + t) >> 5;
    if (node >= n) return;
    const int start = row_ptr[node];
    const int end   = row_ptr[node + 1];
    float a0 = 0.f, a1 = 0.f;
    for (int base = start; base < end; base += 32) {
        const int idx = base + sl;
        unsigned long long pc = (idx < end) ? cpack[idx] : 0ULL;
        int   c = (int)(unsigned)pc;
        float v = __uint_as_float((unsigned)(pc >> 32));
        const int cnt = min(32, end - base);
        int e = 0;
        for (; e + 4 <= cnt; e += 4) {
            int   c0 = __shfl(c, e, 32),     c1 = __shfl(c, e + 1, 32);
            int   c2 = __shfl(c, e + 2, 32), c3 = __shfl(c, e + 3, 32);
            float v0 = __shfl(v, e, 32),     v1 = __shfl(v, e + 1, 32);
            float v2 = __shfl(v, e + 2, 32), v3 = __shfl(v, e + 3, 32);
            unsigned g0 = h_in[(size_t)c0 * 32 + sl];
            unsigned g1 = h_in[(size_t)c1 * 32 + sl];
            unsigned g2 = h_in[(size_t)c2 * 32 + sl];
            unsigned g3 = h_in[(size_t)c3 * 32 + sl];
            a0 = fmaf(v0, bflo(g0), a0); a1 = fmaf(v0, bfhi(g0), a1);
            a0 = fmaf(v1, bflo(g1), a0); a1 = fmaf(v1, bfhi(g1), a1);
            a0 = fmaf(v2, bflo(g2), a0); a1 = fmaf(v2, bfhi(g2), a1);
            a0 = fmaf(v3, bflo(g3), a0); a1 = fmaf(v3, bfhi(g3), a1);
        }
        for (; e < cnt; ++e) {
            int   cc = __shfl(c, e, 32);
            float vv = __shfl(v, e, 32);
            unsigned g = h_in[(size_t)cc * 32 + sl];
            a0 = fmaf(vv, bflo(g), a0); a1 = fmaf(vv, bfhi(g), a1);
        }
    }
    h_out[(size_t)node * 32 + sl] = pk2(a0, a1);
}

// ---------------------------------------------------------------------------
// Final combine: sig_k(n) = sigmoid(h_k(n).s); out = sum_k sig_k(n) h_k(n)
// ---------------------------------------------------------------------------
__global__ __launch_bounds__(256) void k_combine(
    const unsigned* __restrict__ hbuf, const float* __restrict__ s,
    float* __restrict__ out, int n)
{
    const int gid  = blockIdx.x * 256 + threadIdx.x;
    const int node = gid >> 5, sl = gid & 31;
    if (node >= n) return;
    const float2 sv = ((const float2*)s)[sl];
    float o0 = 0.f, o1 = 0.f;
    #pragma unroll
    for (int k = 0; k <= HOPS; ++k) {
        const unsigned g = hbuf[(size_t)k * n * 32 + (size_t)node * 32 + sl];
        const float lo = bflo(g), hi = bfhi(g);
        float tv = lo * sv.x + hi * sv.y;
        #pragma unroll
        for (int off = 16; off > 0; off >>= 1) tv += __shfl_xor(tv, off, 32);
        const float sg = 1.f / (1.f + expf(-tv));
        o0 = fmaf(sg, lo, o0);
        o1 = fmaf(sg, hi, o1);
    }
    float2 ov; ov.x = o0; ov.y = o1;
    ((float2*)out)[(size_t)node * 32 + sl] = ov;
}

// ---------------------------------------------------------------------------
extern "C" void kernel_launch(void* const* d_in, const int* in_sizes, int n_in,
                              void* d_out, int out_size, void* d_ws, size_t ws_size,
                              hipStream_t stream)
{
    const float* x  = (const float*)d_in[0];
    const int*   er = (const int*)  d_in[1];
    const int*   ec = (const int*)  d_in[2];
    const float* ev = (const float*)d_in[3];
    const float* W1 = (const float*)d_in[4];
    const float* b1 = (const float*)d_in[5];
    const float* W2 = (const float*)d_in[6];
    const float* b2 = (const float*)d_in[7];
    const float* s  = (const float*)d_in[8];
    float* out = (float*)d_out;

    const int n = in_sizes[0] / NIN;   // 100000
    const int e = in_sizes[1];         // 1600000
    const int nbk = (n + 255) >> 8;    // 391 buckets

    // workspace carve (256B aligned): ~185 MB of ~800 MB ws
    char* w = (char*)d_ws;
    auto carve = [&](size_t bytes) { char* p = w; w += (bytes + 255) & ~(size_t)255; return p; };
    unsigned* hbuf   = (unsigned*)carve((size_t)(HOPS + 1) * n * 32 * 4);  // 140.8 MB
    int*      rp     = (int*)     carve(((size_t)n + 1) * 4);
    unsigned long long* cpack = (unsigned long long*)carve((size_t)e * 8); // 12.8 MB
    uint4*    brec   = (uint4*)   carve((size_t)e * 16);                   // 25.6 MB
    int*      bcnt   = (int*)     carve(512 * 4);
    int*      bbase  = (int*)     carve(513 * 4);
    int*      gcur   = (int*)     carve(512 * 16 * 4);
    unsigned short* W1f = (unsigned short*)carve((size_t)NHID * NIN * 2);
    unsigned short* W2f = (unsigned short*)carve((size_t)NOUT * NHID * 2);

    hipMemsetAsync(bcnt, 0, 512 * 4, stream);

    k_preconv<<<(NHID * NIN + 255) / 256, 256, 0, stream>>>(W1, W2, W1f, W2f);

    const int mgrid = (n + 63) / 64;
    mlp_kernel<<<mgrid, 256, 0, stream>>>(x, W1f, b1, W2f, b2, hbuf, n);

    kA_hist <<<256, 256, 0, stream>>>(er, bcnt, e, nbk);
    kB_scan <<<1, 512, 0, stream>>>(bcnt, bbase, gcur, e, nbk);
    k_bapp  <<<(e + 4095) / 4096, 256, 0, stream>>>(er, ec, ev, gcur, brec, e, nbk);
    k_brow  <<<nbk, 256, 0, stream>>>(brec, bbase, rp, n, e);
    k_bwrite<<<nbk, 256, 0, stream>>>(brec, bbase, rp, cpack);

    const int hgrid = ((size_t)n * 32 + 255) / 256;
    for (int hop = 0; hop < HOPS; ++hop) {
        hop_kernel<<<hgrid, 256, 0, stream>>>(
            hbuf + (size_t)hop * n * 32, hbuf + (size_t)(hop + 1) * n * 32,
            rp, cpack, n);
    }

    k_combine<<<hgrid, 256, 0, stream>>>(hbuf, s, out, n);
}

// Round 10
// 512.845 us; speedup vs baseline: 1.6510x; 1.0304x over previous
//
#include <hip/hip_runtime.h>
#include <hip/hip_bf16.h>

#define NIN  512
#define NHID 256
#define NOUT 64
#define HOPS 10

typedef __attribute__((ext_vector_type(8))) short bf16x8;
typedef __attribute__((ext_vector_type(4))) float f32x4;

__device__ __forceinline__ unsigned short f2bf(float f) {
    unsigned u = __float_as_uint(f);
    u += 0x7FFFu + ((u >> 16) & 1u);            // RNE
    return (unsigned short)(u >> 16);
}
__device__ __forceinline__ unsigned pk2(float a, float b) {
    return (unsigned)f2bf(a) | ((unsigned)f2bf(b) << 16);
}
__device__ __forceinline__ float bflo(unsigned g) { return __uint_as_float(g << 16); }
__device__ __forceinline__ float bfhi(unsigned g) { return __uint_as_float(g & 0xFFFF0000u); }

// ---------------------------------------------------------------------------
// Pre-permute W1, W2 into MFMA A-fragment order (bf16).  (verified R4/R5)
// ---------------------------------------------------------------------------
__global__ void k_preconv(const float* __restrict__ W1, const float* __restrict__ W2,
                          unsigned short* __restrict__ W1f, unsigned short* __restrict__ W2f)
{
    const int i = blockIdx.x * 256 + threadIdx.x;
    if (i < NHID * NIN) {
        const int j = i & 7, l = (i >> 3) & 63, fi = i >> 9;
        const int ks = fi >> 4, w = (fi >> 2) & 3, nf = fi & 3;
        const int col = w * 64 + nf * 16 + (l & 15);
        const int k   = ks * 32 + ((l >> 4) << 3) + j;
        W1f[i] = f2bf(W1[col * NIN + k]);
    }
    if (i < NOUT * NHID) {
        const int j = i & 7, l = (i >> 3) & 63, fi = i >> 9;
        const int ks = fi >> 2, nf = fi & 3;
        const int col = nf * 16 + (l & 15);
        const int k   = ks * 32 + ((j >> 2) << 4) + ((l >> 4) << 2) + (j & 3);
        W2f[i] = f2bf(W2[col * NHID + k]);
    }
}

// ---------------------------------------------------------------------------
// Fused MFMA MLP (operand-swapped, verified R4-R9). Outputs bf16-packed h0.
// ---------------------------------------------------------------------------
__global__ __launch_bounds__(256, 3) void mlp_kernel(
    const float* __restrict__ x, const unsigned short* __restrict__ W1f,
    const float* __restrict__ b1, const unsigned short* __restrict__ W2f,
    const float* __restrict__ b2,
    unsigned* __restrict__ hpack, int n)
{
    __shared__ __align__(16) char smem[50176];
    short* B2L  = (short*)smem;
    short* BX   = (short*)(smem + 32768);
    float* H0L  = (float*)(smem + 32768);

    const int t  = threadIdx.x;
    const int w  = t >> 6, lz = t & 63;
    const int row0 = blockIdx.x * 64;

    const int srow = t >> 2;
    int xrow = row0 + srow; if (xrow >= n) xrow = n - 1;
    const float4* xp = (const float4*)(x + (size_t)xrow * NIN);
    const int q4a = t & 3, q4b = (t & 3) + 4;

    f32x4 acc[4][4];
    #pragma unroll
    for (int a = 0; a < 4; ++a)
        #pragma unroll
        for (int b = 0; b < 4; ++b) acc[a][b] = (f32x4)(0.f);

    auto xwrite = [&](int b, float4 va, float4 vb) {
        unsigned long long pa = (unsigned long long)pk2(va.x, va.y)
                              | ((unsigned long long)pk2(va.z, va.w) << 32);
        unsigned long long pb = (unsigned long long)pk2(vb.x, vb.y)
                              | ((unsigned long long)pk2(vb.z, vb.w) << 32);
        *(unsigned long long*)&BX[(((((b << 2) + (srow >> 4)) << 6)
            + ((srow & 15) | ((q4a >> 1) << 4))) << 3) + ((q4a & 1) << 2)] = pa;
        *(unsigned long long*)&BX[(((((b << 2) + (srow >> 4)) << 6)
            + ((srow & 15) | ((q4b >> 1) << 4))) << 3) + ((q4b & 1) << 2)] = pb;
    };
    auto wload = [&](int kt, bf16x8* wf) {
        const unsigned short* wp = W1f + ((size_t)kt << 13) + (w << 11) + (lz << 3);
        #pragma unroll
        for (int hf = 0; hf < 4; ++hf)
            wf[hf] = *(const bf16x8*)(wp + (hf << 9));
    };
    auto compute = [&](int b, const bf16x8* wf) {
        bf16x8 xf[4];
        #pragma unroll
        for (int nfn = 0; nfn < 4; ++nfn)
            xf[nfn] = *(const bf16x8*)&BX[((((b << 2) + nfn) << 6) + lz) << 3];
        #pragma unroll
        for (int nfn = 0; nfn < 4; ++nfn)
            #pragma unroll
            for (int hf = 0; hf < 4; ++hf)
                acc[nfn][hf] = __builtin_amdgcn_mfma_f32_16x16x32_bf16(
                    wf[hf], xf[nfn], acc[nfn][hf], 0, 0, 0);
    };

    bf16x8 wfc[4], wfn[4];
    float4 sAa, sAb, sBa, sBb;
    {
        float4 xa = xp[q4a], xb = xp[q4b];
        wload(0, wfc);
        xwrite(0, xa, xb);
        sAa = xp[8 + q4a]; sAb = xp[8 + q4b];
    }
    __syncthreads();

    #pragma unroll 1
    for (int kt = 0; kt < 16; kt += 2) {
        if (kt + 2 < 16) { sBa = xp[((kt + 2) << 3) + q4a]; sBb = xp[((kt + 2) << 3) + q4b]; }
        wload(kt + 1, wfn);
        compute(0, wfc);
        xwrite(1, sAa, sAb);
        __syncthreads();
        if (kt + 3 < 16) { sAa = xp[((kt + 3) << 3) + q4a]; sAb = xp[((kt + 3) << 3) + q4b]; }
        if (kt + 2 < 16) wload(kt + 2, wfc);
        compute(1, wfn);
        if (kt + 2 < 16) xwrite(0, sBa, sBb);
        __syncthreads();
    }

    {
        float4 b1q[4];
        #pragma unroll
        for (int hf = 0; hf < 4; ++hf)
            b1q[hf] = *(const float4*)(b1 + (w << 6) + (hf << 4) + ((lz >> 4) << 2));
        #pragma unroll
        for (int nfn = 0; nfn < 4; ++nfn) {
            #pragma unroll
            for (int cl = 0; cl < 2; ++cl) {
                f32x4 a0 = acc[nfn][2 * cl], a1 = acc[nfn][2 * cl + 1];
                float4 c0 = b1q[2 * cl], c1 = b1q[2 * cl + 1];
                uint4 pv;
                pv.x = pk2(fmaxf(a0.x + c0.x, 0.f), fmaxf(a0.y + c0.y, 0.f));
                pv.y = pk2(fmaxf(a0.z + c0.z, 0.f), fmaxf(a0.w + c0.w, 0.f));
                pv.z = pk2(fmaxf(a1.x + c1.x, 0.f), fmaxf(a1.y + c1.y, 0.f));
                pv.w = pk2(fmaxf(a1.z + c1.z, 0.f), fmaxf(a1.w + c1.w, 0.f));
                *(uint4*)&B2L[((((nfn << 3) + (w << 1) + cl) << 6) + lz) << 3] = pv;
            }
        }
    }
    __syncthreads();

    f32x4 acc2[4];
    #pragma unroll
    for (int nf2 = 0; nf2 < 4; ++nf2) acc2[nf2] = (f32x4)(0.f);

    #pragma unroll
    for (int c = 0; c < 8; ++c) {
        bf16x8 hfrag = *(const bf16x8*)&B2L[((((w << 3) + c) << 6) + lz) << 3];
        #pragma unroll
        for (int nf2 = 0; nf2 < 4; ++nf2) {
            bf16x8 wfrag = *(const bf16x8*)(W2f + (((c << 2) + nf2) << 9) + (lz << 3));
            acc2[nf2] = __builtin_amdgcn_mfma_f32_16x16x32_bf16(
                wfrag, hfrag, acc2[nf2], 0, 0, 0);
        }
    }

    {
        const int mloc = (w << 4) + (lz & 15);
        #pragma unroll
        for (int nf2 = 0; nf2 < 4; ++nf2) {
            float4 bq = *(const float4*)(b2 + (nf2 << 4) + ((lz >> 4) << 2));
            float4 hv;
            hv.x = acc2[nf2].x + bq.x; hv.y = acc2[nf2].y + bq.y;
            hv.z = acc2[nf2].z + bq.z; hv.w = acc2[nf2].w + bq.w;
            *(float4*)&H0L[mloc * 68 + (nf2 << 4) + ((lz >> 4) << 2)] = hv;
        }
    }
    __syncthreads();

    {
        const int m = t >> 2, q = t & 3;
        const int g = row0 + m;
        if (g < n) {
            unsigned* hp = hpack + (size_t)g * 32 + (q << 3);
            #pragma unroll
            for (int i = 0; i < 16; i += 4) {
                float4 hv = *(const float4*)&H0L[m * 68 + (q << 4) + i];
                uint2 pv;
                pv.x = pk2(hv.x, hv.y);
                pv.y = pk2(hv.z, hv.w);
                *(uint2*)(hp + (i >> 1)) = pv;
            }
        }
    }
}

// ---------------------------------------------------------------------------
// CSR build via single-digit bucket sort (bucket = row >> 8).  (verified R9)
// ---------------------------------------------------------------------------
__global__ __launch_bounds__(256) void kA_hist(
    const int* __restrict__ erow, int* __restrict__ bcnt, int e, int nbk)
{
    __shared__ int lh[512];
    const int t = threadIdx.x;
    for (int b = t; b < 512; b += 256) lh[b] = 0;
    __syncthreads();
    for (int i = blockIdx.x * 256 + t; i < e; i += gridDim.x * 256)
        atomicAdd(&lh[erow[i] >> 8], 1);
    __syncthreads();
    for (int b = t; b < nbk; b += 256)
        if (lh[b]) atomicAdd(&bcnt[b], lh[b]);
}

__global__ __launch_bounds__(512) void kB_scan(
    const int* __restrict__ bcnt, int* __restrict__ bbase,
    int* __restrict__ gcur, int e, int nbk)
{
    __shared__ int sm[512];
    const int tid = threadIdx.x;
    const int v = (tid < nbk) ? bcnt[tid] : 0;
    sm[tid] = v;
    __syncthreads();
    for (int off = 1; off < 512; off <<= 1) {
        int tv = (tid >= off) ? sm[tid - off] : 0;
        __syncthreads();
        sm[tid] += tv;
        __syncthreads();
    }
    if (tid < nbk) {
        const int base = sm[tid] - v;
        bbase[tid] = base;
        gcur[tid * 16] = base;        // 64B-padded cursor
    }
    if (tid == 0) bbase[nbk] = e;
}

__global__ __launch_bounds__(256) void k_bapp(
    const int* __restrict__ erow, const int* __restrict__ ecol,
    const float* __restrict__ ev, int* __restrict__ gcur,
    uint4* __restrict__ brec, int e, int nbk)
{
    __shared__ int lh[512];
    __shared__ int lbase[512];
    const int t = threadIdx.x;
    const int c0 = blockIdx.x * 4096;
    for (int b = t; b < 512; b += 256) lh[b] = 0;
    __syncthreads();
    int rr[16];
    #pragma unroll
    for (int j = 0; j < 16; ++j) {
        const int i = c0 + j * 256 + t;
        rr[j] = (i < e) ? erow[i] : -1;
        if (rr[j] >= 0) atomicAdd(&lh[rr[j] >> 8], 1);
    }
    __syncthreads();
    for (int b = t; b < nbk; b += 256) {
        const int c = lh[b];
        lbase[b] = c ? atomicAdd(&gcur[b * 16], c) : 0;
        lh[b] = 0;
    }
    __syncthreads();
    #pragma unroll
    for (int j = 0; j < 16; ++j) {
        const int i = c0 + j * 256 + t;
        if (rr[j] >= 0) {
            const int b  = rr[j] >> 8;
            const int rk = atomicAdd(&lh[b], 1);
            uint4 rec;
            rec.x = (unsigned)rr[j];
            rec.y = (unsigned)ecol[i];
            rec.z = __float_as_uint(ev[i]);
            rec.w = 0;
            brec[lbase[b] + rk] = rec;
        }
    }
}

__global__ __launch_bounds__(256) void k_brow(
    const uint4* __restrict__ brec, const int* __restrict__ bbase,
    int* __restrict__ rp, int n, int e)
{
    __shared__ int rc[256];
    __shared__ int sc[256];
    const int b = blockIdx.x, t = threadIdx.x;
    const int lo = bbase[b], hi = bbase[b + 1];
    rc[t] = 0;
    __syncthreads();
    for (int i = lo + t; i < hi; i += 256) {
        const unsigned r = ((const unsigned*)brec)[(size_t)i * 4];
        atomicAdd(&rc[r & 255], 1);
    }
    __syncthreads();
    const int v = rc[t];
    sc[t] = v;
    __syncthreads();
    for (int off = 1; off < 256; off <<= 1) {
        int tv = (t >= off) ? sc[t - off] : 0;
        __syncthreads();
        sc[t] += tv;
        __syncthreads();
    }
    const int row = (b << 8) + t;
    if (row < n) rp[row] = lo + sc[t] - v;
    if (b == 0 && t == 0) rp[n] = e;
}

__global__ __launch_bounds__(256) void k_bwrite(
    const uint4* __restrict__ brec, const int* __restrict__ bbase,
    const int* __restrict__ rp, unsigned long long* __restrict__ cpack)
{
    __shared__ int rc[256];
    const int b = blockIdx.x, t = threadIdx.x;
    const int lo = bbase[b], hi = bbase[b + 1];
    rc[t] = 0;
    __syncthreads();
    for (int i = lo + t; i < hi; i += 256) {
        const uint4 rec = brec[i];
        const int rk = atomicAdd(&rc[rec.x & 255], 1);
        cpack[rp[rec.x] + rk] = ((unsigned long long)rec.z << 32) | rec.y;
    }
}

// ---------------------------------------------------------------------------
// One propagation hop (pull, CSR, bf16-packed h). 8-deep gather pipeline
// (latency-bound fix: 4 -> 8 concurrent LLC gathers per wave-half).
// ---------------------------------------------------------------------------
__global__ __launch_bounds__(256) void hop_kernel(
    const unsigned* __restrict__ h_in, unsigned* __restrict__ h_out,
    const int* __restrict__ row_ptr, const unsigned long long* __restrict__ cpack,
    int n)
{
    const int t  = threadIdx.x;
    const int sl = t & 31;
    const int node = (blockIdx.x * 256 + t) >> 5;
    if (node >= n) return;
    const int start = row_ptr[node];
    const int end   = row_ptr[node + 1];
    float a0 = 0.f, a1 = 0.f;
    for (int base = start; base < end; base += 32) {
        const int idx = base + sl;
        unsigned long long pc = (idx < end) ? cpack[idx] : 0ULL;
        int   c = (int)(unsigned)pc;
        float v = __uint_as_float((unsigned)(pc >> 32));
        const int cnt = min(32, end - base);
        int e = 0;
        for (; e + 8 <= cnt; e += 8) {           // 8 gathers in flight
            int cc[8]; float vv[8]; unsigned gg[8];
            #pragma unroll
            for (int j = 0; j < 8; ++j) {
                cc[j] = __shfl(c, e + j, 32);
                vv[j] = __shfl(v, e + j, 32);
            }
            #pragma unroll
            for (int j = 0; j < 8; ++j)
                gg[j] = h_in[(size_t)cc[j] * 32 + sl];
            #pragma unroll
            for (int j = 0; j < 8; ++j) {
                a0 = fmaf(vv[j], bflo(gg[j]), a0);
                a1 = fmaf(vv[j], bfhi(gg[j]), a1);
            }
        }
        for (; e + 4 <= cnt; e += 4) {
            int cc[4]; float vv[4]; unsigned gg[4];
            #pragma unroll
            for (int j = 0; j < 4; ++j) {
                cc[j] = __shfl(c, e + j, 32);
                vv[j] = __shfl(v, e + j, 32);
            }
            #pragma unroll
            for (int j = 0; j < 4; ++j)
                gg[j] = h_in[(size_t)cc[j] * 32 + sl];
            #pragma unroll
            for (int j = 0; j < 4; ++j) {
                a0 = fmaf(vv[j], bflo(gg[j]), a0);
                a1 = fmaf(vv[j], bfhi(gg[j]), a1);
            }
        }
        for (; e < cnt; ++e) {
            int   cc = __shfl(c, e, 32);
            float vv = __shfl(v, e, 32);
            unsigned g = h_in[(size_t)cc * 32 + sl];
            a0 = fmaf(vv, bflo(g), a0); a1 = fmaf(vv, bfhi(g), a1);
        }
    }
    h_out[(size_t)node * 32 + sl] = pk2(a0, a1);
}

// ---------------------------------------------------------------------------
// Final combine: sig_k(n) = sigmoid(h_k(n).s); out = sum_k sig_k(n) h_k(n)
// ---------------------------------------------------------------------------
__global__ __launch_bounds__(256) void k_combine(
    const unsigned* __restrict__ hbuf, const float* __restrict__ s,
    float* __restrict__ out, int n)
{
    const int gid  = blockIdx.x * 256 + threadIdx.x;
    const int node = gid >> 5, sl = gid & 31;
    if (node >= n) return;
    const float2 sv = ((const float2*)s)[sl];
    float o0 = 0.f, o1 = 0.f;
    #pragma unroll
    for (int k = 0; k <= HOPS; ++k) {
        const unsigned g = hbuf[(size_t)k * n * 32 + (size_t)node * 32 + sl];
        const float lo = bflo(g), hi = bfhi(g);
        float tv = lo * sv.x + hi * sv.y;
        #pragma unroll
        for (int off = 16; off > 0; off >>= 1) tv += __shfl_xor(tv, off, 32);
        const float sg = 1.f / (1.f + expf(-tv));
        o0 = fmaf(sg, lo, o0);
        o1 = fmaf(sg, hi, o1);
    }
    float2 ov; ov.x = o0; ov.y = o1;
    ((float2*)out)[(size_t)node * 32 + sl] = ov;
}

// ---------------------------------------------------------------------------
extern "C" void kernel_launch(void* const* d_in, const int* in_sizes, int n_in,
                              void* d_out, int out_size, void* d_ws, size_t ws_size,
                              hipStream_t stream)
{
    const float* x  = (const float*)d_in[0];
    const int*   er = (const int*)  d_in[1];
    const int*   ec = (const int*)  d_in[2];
    const float* ev = (const float*)d_in[3];
    const float* W1 = (const float*)d_in[4];
    const float* b1 = (const float*)d_in[5];
    const float* W2 = (const float*)d_in[6];
    const float* b2 = (const float*)d_in[7];
    const float* s  = (const float*)d_in[8];
    float* out = (float*)d_out;

    const int n = in_sizes[0] / NIN;   // 100000
    const int e = in_sizes[1];         // 1600000
    const int nbk = (n + 255) >> 8;    // 391 buckets

    char* w = (char*)d_ws;
    auto carve = [&](size_t bytes) { char* p = w; w += (bytes + 255) & ~(size_t)255; return p; };
    unsigned* hbuf   = (unsigned*)carve((size_t)(HOPS + 1) * n * 32 * 4);  // 140.8 MB
    int*      rp     = (int*)     carve(((size_t)n + 1) * 4);
    unsigned long long* cpack = (unsigned long long*)carve((size_t)e * 8); // 12.8 MB
    uint4*    brec   = (uint4*)   carve((size_t)e * 16);                   // 25.6 MB
    int*      bcnt   = (int*)     carve(512 * 4);
    int*      bbase  = (int*)     carve(513 * 4);
    int*      gcur   = (int*)     carve(512 * 16 * 4);
    unsigned short* W1f = (unsigned short*)carve((size_t)NHID * NIN * 2);
    unsigned short* W2f = (unsigned short*)carve((size_t)NOUT * NHID * 2);

    hipMemsetAsync(bcnt, 0, 512 * 4, stream);

    k_preconv<<<(NHID * NIN + 255) / 256, 256, 0, stream>>>(W1, W2, W1f, W2f);

    const int mgrid = (n + 63) / 64;
    mlp_kernel<<<mgrid, 256, 0, stream>>>(x, W1f, b1, W2f, b2, hbuf, n);

    kA_hist <<<256, 256, 0, stream>>>(er, bcnt, e, nbk);
    kB_scan <<<1, 512, 0, stream>>>(bcnt, bbase, gcur, e, nbk);
    k_bapp  <<<(e + 4095) / 4096, 256, 0, stream>>>(er, ec, ev, gcur, brec, e, nbk);
    k_brow  <<<nbk, 256, 0, stream>>>(brec, bbase, rp, n, e);
    k_bwrite<<<nbk, 256, 0, stream>>>(brec, bbase, rp, cpack);

    const int hgrid = ((size_t)n * 32 + 255) / 256;
    for (int hop = 0; hop < HOPS; ++hop) {
        hop_kernel<<<hgrid, 256, 0, stream>>>(
            hbuf + (size_t)hop * n * 32, hbuf + (size_t)(hop + 1) * n * 32,
            rp, cpack, n);
    }

    k_combine<<<hgrid, 256, 0, stream>>>(hbuf, s, out, n);
}